// Round 11
// baseline (149.510 us; speedup 1.0000x reference)
//
#include <hip/hip_runtime.h>
#include <math.h>

#define BB 16
#define SS 512
#define HH 1024
#define KT 5
#define NEGV 1e30f

typedef __attribute__((ext_vector_type(8))) short short8_t;
typedef __attribute__((ext_vector_type(4))) float f32x4;

// ---------------- helpers ----------------
__device__ __forceinline__ float wave_sum(float v) {
    for (int off = 32; off; off >>= 1) v += __shfl_down(v, off);
    return v;
}

__device__ __forceinline__ unsigned short bf16rn(float x) {
    unsigned u = __float_as_uint(x);
    return (unsigned short)((u + 0x7fffu + ((u >> 16) & 1u)) >> 16);
}

__device__ __forceinline__ void split2(float x, unsigned short& h, unsigned short& l) {
    h = bf16rn(x);
    float hf = __uint_as_float(((unsigned)h) << 16);
    l = bf16rn(x - hf);
}

__device__ __forceinline__ float tanh_fast(float x) {
    float e = __expf(2.0f * x);
    return 1.0f - 2.0f * __builtin_amdgcn_rcpf(e + 1.0f);
}

// async global->LDS, 16B per lane; lds dst must be wave-uniform base
__device__ __forceinline__ void gld16(const short* g, char* l) {
    __builtin_amdgcn_global_load_lds((const __attribute__((address_space(1))) void*)g,
                                     (__attribute__((address_space(3))) void*)l, 16, 0, 0);
}

// ---------------- softmax + top-5 over 512 values held as (x0,x1) per thread ----------------
template <bool WRITE_P>
__device__ void softmax_topk_vals(float x0, float x1, float* __restrict__ p_out,
                                  float* __restrict__ val_out, float* __restrict__ idxf_out,
                                  int* __restrict__ idxi_out) {
    const int t = threadIdx.x;
    __shared__ float scr[4];
    __shared__ float sv[4];
    __shared__ int si[4];
    __shared__ int wi_s;

    float m = fmaxf(x0, x1);
    for (int off = 32; off; off >>= 1) m = fmaxf(m, __shfl_down(m, off));
    if ((t & 63) == 0) scr[t >> 6] = m;
    __syncthreads();
    m = fmaxf(fmaxf(scr[0], scr[1]), fmaxf(scr[2], scr[3]));
    __syncthreads();

    float e0 = expf(x0 - m), e1 = expf(x1 - m);
    float ssum = wave_sum(e0 + e1);
    if ((t & 63) == 0) scr[t >> 6] = ssum;
    __syncthreads();
    ssum = scr[0] + scr[1] + scr[2] + scr[3];
    __syncthreads();

    if (WRITE_P) {
        p_out[t] = e0 / ssum;
        p_out[t + 256] = e1 / ssum;
    }
    const float lse = m + logf(ssum);

    float v0 = x0, v1 = x1;
    for (int k = 0; k < KT; ++k) {
        float bv;
        int bi;
        if (v0 >= v1) { bv = v0; bi = t; } else { bv = v1; bi = t + 256; }
        for (int off = 32; off; off >>= 1) {
            float ov = __shfl_down(bv, off);
            int oi = __shfl_down(bi, off);
            if (ov > bv || (ov == bv && oi < bi)) { bv = ov; bi = oi; }
        }
        if ((t & 63) == 0) { sv[t >> 6] = bv; si[t >> 6] = bi; }
        __syncthreads();
        if (t == 0) {
            float fv = sv[0];
            int fi = si[0];
            for (int w = 1; w < 4; ++w)
                if (sv[w] > fv || (sv[w] == fv && si[w] < fi)) { fv = sv[w]; fi = si[w]; }
            wi_s = fi;
            val_out[k] = fv - lse;
            idxf_out[k] = (float)fi;
            if (idxi_out) idxi_out[k] = fi;
        }
        __syncthreads();
        const int wi = wi_s;
        if (wi == t) v0 = -INFINITY;
        else if (wi == t + 256) v1 = -INFINITY;
        __syncthreads();
    }
}

// ---------------- K1 mega_prep: seqpk | prep | start_logits | scal ----------------
// grid = 4096 (seqpk) + 512 (prep) + 2048 (start_logits) + 1 (scal) = 6657
__global__ void k_mega(const float* __restrict__ seq, const float* __restrict__ w_end0,
                       const float* __restrict__ pm, const float* __restrict__ w_start,
                       const float* __restrict__ b_start, const float* __restrict__ ln_g,
                       const float* __restrict__ ln_b, const float* __restrict__ w_end1,
                       short* __restrict__ wpk_hi, short* __restrict__ wpk_lo,
                       short* __restrict__ apk_hi, short* __restrict__ apk_lo,
                       float* __restrict__ sm, float* __restrict__ scal) {
    const int bid = blockIdx.x;
    const int t = threadIdx.x;
    __shared__ float scr8[8];

    if (bid < 4096) {
        // ---- seqpk: pack seq into MFMA A-frag order (bf16 hi/lo) ----
        // Apk layout: [bm(64)][ks(32)][mtl(8)][lane(64)][8] bf16
        const size_t g = (size_t)bid * 256 + t;
        const int l = g & 63;
        const int mtl = (g >> 6) & 7;
        const int ks = (g >> 9) & 31;
        const int bm = g >> 14;
        const int row = bm * 128 + mtl * 16 + (l & 15);
        const int k0 = ks * 32 + (l >> 4) * 8;
        const float4 v0 = *(const float4*)(seq + (size_t)row * HH + k0);
        const float4 v1 = *(const float4*)(seq + (size_t)row * HH + k0 + 4);
        float xs[8] = {v0.x, v0.y, v0.z, v0.w, v1.x, v1.y, v1.z, v1.w};
        unsigned short h[8], lo[8];
#pragma unroll
        for (int j = 0; j < 8; ++j) split2(xs[j], h[j], lo[j]);
        short8_t hv, lv;
#pragma unroll
        for (int j = 0; j < 8; ++j) { hv[j] = (short)h[j]; lv[j] = (short)lo[j]; }
        *(short8_t*)(apk_hi + g * 8) = hv;
        *(short8_t*)(apk_lo + g * 8) = lv;
    } else if (bid < 4608) {
        // ---- prep: pack W0a into MFMA B-frag order (bf16 hi/lo) ----
        const int bid2 = bid - 4096;
        const int nt = bid2 & 63;
        const int yy = bid2 >> 6;
        const int n_idx = t & 15;
        const int g = (t >> 4) & 3;
        const int kq = t >> 6;
        const int kblk = yy * 4 + kq;
        const int k0 = kblk * 32 + g * 8;
        unsigned short hs[8], ls[8];
#pragma unroll
        for (int j = 0; j < 8; ++j) {
            float v = w_end0[(size_t)(k0 + j) * HH + nt * 16 + n_idx];
            split2(v, hs[j], ls[j]);
        }
        const size_t fi = (((size_t)nt * 32 + kblk) * 64 + (g * 16 + n_idx)) * 8;
        short8_t hv, lv;
#pragma unroll
        for (int j = 0; j < 8; ++j) { hv[j] = (short)hs[j]; lv[j] = (short)ls[j]; }
        *(short8_t*)(wpk_hi + fi) = hv;
        *(short8_t*)(wpk_lo + fi) = lv;
    } else if (bid < 6656) {
        // ---- start_logits: wave per row ----
        const int l = t & 63;
        const int row = (bid - 4608) * 4 + (t >> 6);
        const float4* rp = (const float4*)(seq + (size_t)row * HH);
        const float4* wp = (const float4*)w_start;
        float d = 0.f;
#pragma unroll
        for (int q = 0; q < 4; ++q) {
            float4 a = rp[q * 64 + l];
            float4 w = wp[q * 64 + l];
            d += a.x * w.x + a.y * w.y + a.z * w.z + a.w * w.w;
        }
        d = wave_sum(d);
        if (l == 0) {
            float m = pm[row];
            sm[row] = (d + b_start[0]) * (1.f - m) - NEGV * m;
        }
    } else {
        // ---- scal: GW1 = sum g*w1, BW1 = sum b*w1 ----
        float4 g = ((const float4*)ln_g)[t];
        float4 w = ((const float4*)w_end1)[t];
        float4 b = ((const float4*)ln_b)[t];
        float gw = g.x * w.x + g.y * w.y + g.z * w.z + g.w * w.w;
        float bw = b.x * w.x + b.y * w.y + b.z * w.z + b.w * w.w;
        gw = wave_sum(gw);
        bw = wave_sum(bw);
        if ((t & 63) == 0) { scr8[t >> 6] = gw; scr8[4 + (t >> 6)] = bw; }
        __syncthreads();
        if (t == 0) {
            scal[0] = scr8[0] + scr8[1] + scr8[2] + scr8[3];
            scal[1] = scr8[4] + scr8[5] + scr8[6] + scr8[7];
        }
    }
}

// ---------------- K2: softmax_start (start top-5 + probs) ----------------
__global__ void k_softmax_start(const float* __restrict__ sm, float* __restrict__ sp,
                                float* __restrict__ dout, int* __restrict__ idx) {
    const int b = blockIdx.x;
    const int t = threadIdx.x;
    const float* x = sm + (size_t)b * SS;
    softmax_topk_vals<true>(x[t], x[t + 256], sp + (size_t)b * SS,
                            dout + b * KT, dout + 80 + b * KT, idx + b * KT);
}

// ---------------- K3 mid: cfeat (512 blocks) | sf_partial (512 blocks) ----------------
__global__ void k_mid(const float* __restrict__ seq, const int* __restrict__ idx,
                      const float* __restrict__ w_end0, float* __restrict__ Cpart,
                      const float* __restrict__ sp, float* __restrict__ partial) {
    __shared__ float shA[80 * 132];
    __shared__ float shW[16 * 132];
    __shared__ int growL[80];
    const int bid = blockIdx.x;
    const int t = threadIdx.x;

    if (bid < 512) {
        // ---- cfeat: Cb partials, K-split ----
        const int c = bid & 63;
        const int kc = bid >> 6;
        if (t < 80) growL[t] = (t / KT) * SS + idx[t];
        __syncthreads();
        for (int i = 0; i < 40; ++i) {
            const int e = i * 256 + t;
            const int r = e >> 7, d = e & 127;
            shA[r * 132 + d] = seq[(size_t)growL[r] * HH + kc * 128 + d];
        }
#pragma unroll
        for (int p = 0; p < 8; ++p) {
            const int e = p * 256 + t;
            const int d = e >> 4, j = e & 15;
            shW[j * 132 + d] = w_end0[(size_t)(HH + kc * 128 + d) * HH + c * 16 + j];
        }
        __syncthreads();
        const int j = t & 15, rg = t >> 4;
        const float4* A4 = (const float4*)shA;
        const float4* W4 = (const float4*)shW;
        float acc[5] = {0.f, 0.f, 0.f, 0.f, 0.f};
        for (int d4 = 0; d4 < 32; ++d4) {
            float4 wv = W4[j * 33 + d4];
#pragma unroll
            for (int i = 0; i < 5; ++i) {
                float4 av = A4[(rg + 16 * i) * 33 + d4];
                acc[i] += av.x * wv.x + av.y * wv.y + av.z * wv.z + av.w * wv.w;
            }
        }
#pragma unroll
        for (int i = 0; i < 5; ++i)
            Cpart[((size_t)kc * 80 + rg + 16 * i) * HH + c * 16 + j] = acc[i];
    } else {
        // ---- sf_partial: start_feature partial sums (16-row chunks) ----
        const int bid2 = bid - 512;
        const int chunk = bid2 & 31;
        const int b = bid2 >> 5;
        if (t < 16) shA[t] = sp[b * SS + chunk * 16 + t];
        __syncthreads();
        float4 acc = make_float4(0.f, 0.f, 0.f, 0.f);
        const float4* base = (const float4*)(seq + ((size_t)b * SS + chunk * 16) * HH);
        for (int s = 0; s < 16; ++s) {
            float4 v = base[(size_t)s * 256 + t];
            float ps = shA[s];
            acc.x = fmaf(ps, v.x, acc.x);
            acc.y = fmaf(ps, v.y, acc.y);
            acc.z = fmaf(ps, v.z, acc.z);
            acc.w = fmaf(ps, v.w, acc.w);
        }
        ((float4*)partial)[(size_t)(b * 32 + chunk) * 256 + t] = acc;
    }
}

// ---------------- K4 red: cbred (80) | featsum (16) ----------------
__global__ void k_red(const float* __restrict__ Cpart, const float* __restrict__ b_end0,
                      float* __restrict__ Cb, const float* __restrict__ seq,
                      const float* __restrict__ partial, float* __restrict__ feat) {
    const int bid = blockIdx.x;
    const int t = threadIdx.x;
    if (bid < 80) {
        const int bk = bid;
#pragma unroll
        for (int q = 0; q < 4; ++q) {
            const int h = q * 256 + t;
            float s = b_end0[h];
#pragma unroll
            for (int kc = 0; kc < 8; ++kc) s += Cpart[((size_t)kc * 80 + bk) * HH + h];
            Cb[(size_t)bk * HH + h] = s;
        }
    } else {
        const int b = bid - 80;
        for (int q = 0; q < 4; ++q) {
            const int h = q * 256 + t;
            float s = 0.f;
            for (int c = 0; c < 32; ++c) s += partial[(size_t)(b * 32 + c) * HH + h];
            feat[(size_t)b * 2048 + h] = s;
            feat[(size_t)b * 2048 + HH + h] = seq[(size_t)b * SS * HH + h];
        }
    }
}

// ---------------- K5: ans-head GEMM partials, K-split (1024 blocks) ----------------
__global__ void k_ans(const float* __restrict__ feat, const float* __restrict__ w_ans0,
                      float* __restrict__ anspart) {
    __shared__ float A[16 * 132];
    __shared__ float W[16 * 132];
    const int c = blockIdx.x & 63;
    const int kc = blockIdx.x >> 6;
    const int t = threadIdx.x;
#pragma unroll
    for (int i = 0; i < 8; ++i) {
        const int e = i * 256 + t;
        const int b = e >> 7, d = e & 127;
        A[b * 132 + d] = feat[(size_t)b * 2048 + kc * 128 + d];
    }
#pragma unroll
    for (int p = 0; p < 8; ++p) {
        const int e = p * 256 + t;
        const int d = e >> 4, j = e & 15;
        W[j * 132 + d] = w_ans0[(size_t)(kc * 128 + d) * HH + c * 16 + j];
    }
    __syncthreads();
    const int j = t & 15, b = t >> 4;
    const float4* A4 = (const float4*)A;
    const float4* W4 = (const float4*)W;
    float acc = 0.f;
    for (int d4 = 0; d4 < 32; ++d4) {
        float4 wv = W4[j * 33 + d4];
        float4 av = A4[b * 33 + d4];
        acc += av.x * wv.x + av.y * wv.y + av.z * wv.z + av.w * wv.w;
    }
    anspart[((size_t)kc * 16 + b) * HH + c * 16 + j] = acc;
}

// ---------------- K6 k_gemm: split-bf16 MFMA GEMM, 8 waves/block (R6 skeleton) ----------------
// BM=128 x BN=128, BK=32, 8 waves (2x4), wave tile 64x32, 3-term split.
// LDS: 2 x 32KB double-buffer (AH[8][1KB] @0, AL @8K, WH @16K, WL @24K).
// 512 threads -> 2 blocks/CU = 16 waves/CU (vs 8 before): independent-phase
// waves cover each other's barrier/DMA bubbles (m114 mechanism).
// XCD swizzle: each XCD owns an 8bm x 8bn square region.
__global__ __launch_bounds__(512, 4)
void k_gemm(const short* __restrict__ apk_hi, const short* __restrict__ apk_lo,
            const short* __restrict__ wpk_hi, const short* __restrict__ wpk_lo,
            const float* __restrict__ Cb, const float* __restrict__ ln_g,
            const float* __restrict__ w_end1, float* __restrict__ part) {
    extern __shared__ char smem[];  // 65536
    const int t = threadIdx.x;
    const int l = t & 63, w = t >> 6;   // w 0..7
    const int wr = w >> 2, wc = w & 3;  // wave grid 2 x 4; wave tile 64 x 32
    const int wg = blockIdx.x;
    const int xcd = wg & 7;
    const int local = wg >> 3;          // 0..63
    const int bm = xcd * 8 + (local >> 3);
    const int bn = local & 7;
    const int row0 = bm * 128;
    const int b = row0 >> 9;

    f32x4 acc[4][2];
#pragma unroll
    for (int m = 0; m < 4; ++m)
#pragma unroll
        for (int n = 0; n < 2; ++n) acc[m][n] = (f32x4){0.f, 0.f, 0.f, 0.f};

    // per-wave staging: 4 x global_load_lds (1 AH, 1 AL, 1 WH, 1 WL frag = frag index w)
#define STAGE(buf, ks)                                                                   \
    {                                                                                    \
        const size_t abase = (size_t)(bm * 32 + (ks)) * 8 * 512;                         \
        const size_t wbase = ((size_t)(bn * 8) * 32 + (ks)) * 512;                       \
        char* lb = smem + (buf) * 32768;                                                 \
        gld16(apk_hi + abase + w * 512 + l * 8, lb + w * 1024);                          \
        gld16(apk_lo + abase + w * 512 + l * 8, lb + 8192 + w * 1024);                   \
        gld16(wpk_hi + wbase + (size_t)w * 32 * 512 + l * 8, lb + 16384 + w * 1024);     \
        gld16(wpk_lo + wbase + (size_t)w * 32 * 512 + l * 8, lb + 24576 + w * 1024);     \
    }

    STAGE(0, 0);
    __syncthreads();

    for (int ks = 0; ks < 32; ++ks) {
        const int buf = ks & 1;
        if (ks < 31) STAGE(buf ^ 1, ks + 1);
        {
            const char* base_ = smem + buf * 32768;
            short8_t ah[4], al[4], wh[2], wl[2];
#pragma unroll
            for (int m = 0; m < 4; ++m) {
                const int mtl = wr * 4 + m;
                ah[m] = *(const short8_t*)(base_ + (mtl << 10) + (l << 4));
                al[m] = *(const short8_t*)(base_ + 8192 + (mtl << 10) + (l << 4));
            }
#pragma unroll
            for (int n = 0; n < 2; ++n) {
                const int ntl = wc * 2 + n;
                wh[n] = *(const short8_t*)(base_ + 16384 + (ntl << 10) + (l << 4));
                wl[n] = *(const short8_t*)(base_ + 24576 + (ntl << 10) + (l << 4));
            }
            __builtin_amdgcn_s_setprio(1);
#pragma unroll
            for (int n = 0; n < 2; ++n)
#pragma unroll
                for (int m = 0; m < 4; ++m) {
                    acc[m][n] = __builtin_amdgcn_mfma_f32_16x16x32_bf16(ah[m], wh[n], acc[m][n], 0, 0, 0);
                    acc[m][n] = __builtin_amdgcn_mfma_f32_16x16x32_bf16(al[m], wh[n], acc[m][n], 0, 0, 0);
                    acc[m][n] = __builtin_amdgcn_mfma_f32_16x16x32_bf16(ah[m], wl[n], acc[m][n], 0, 0, 0);
                }
            __builtin_amdgcn_s_setprio(0);
        }
        __syncthreads();
    }
#undef STAGE

    // ---- epilogue: per-block partial (S,Q,G) over this 128-col slice ----
    float cbv[KT][2], gwv[2];
#pragma unroll
    for (int n = 0; n < 2; ++n) {
        const int col = bn * 128 + (wc * 2 + n) * 16 + (l & 15);
        gwv[n] = ln_g[col] * w_end1[col];
#pragma unroll
        for (int k = 0; k < KT; ++k) cbv[k][n] = Cb[(size_t)(b * KT + k) * HH + col];
    }
    float* scr = (float*)smem;  // [wc 4][row 128][k 5][3] = 30720 B

    for (int k = 0; k < KT; ++k) {
        float S[4][4], Q[4][4], G[4][4];
#pragma unroll
        for (int m = 0; m < 4; ++m)
#pragma unroll
            for (int r = 0; r < 4; ++r) { S[m][r] = 0.f; Q[m][r] = 0.f; G[m][r] = 0.f; }
#pragma unroll
        for (int n = 0; n < 2; ++n) {
            const float cb = cbv[k][n];
            const float gwn = gwv[n];
#pragma unroll
            for (int m = 0; m < 4; ++m)
#pragma unroll
                for (int r = 0; r < 4; ++r) {
                    float v = tanh_fast(acc[m][n][r] + cb);
                    S[m][r] += v;
                    Q[m][r] += v * v;
                    G[m][r] += v * gwn;
                }
        }
        for (int msk = 1; msk < 16; msk <<= 1) {
#pragma unroll
            for (int m = 0; m < 4; ++m)
#pragma unroll
                for (int r = 0; r < 4; ++r) {
                    S[m][r] += __shfl_xor(S[m][r], msk);
                    Q[m][r] += __shfl_xor(Q[m][r], msk);
                    G[m][r] += __shfl_xor(G[m][r], msk);
                }
        }
        if ((l & 15) == 0) {
            const int gg = l >> 4;
#pragma unroll
            for (int m = 0; m < 4; ++m)
#pragma unroll
                for (int r = 0; r < 4; ++r) {
                    const int row = wr * 64 + m * 16 + gg * 4 + r;
                    float* sp_ = scr + ((wc * 128 + row) * KT + k) * 3;
                    sp_[0] = S[m][r];
                    sp_[1] = Q[m][r];
                    sp_[2] = G[m][r];
                }
        }
    }
    __syncthreads();

#pragma unroll
    for (int i = 0; i < 2; ++i) {
        const int idx = i * 512 + t;  // 640 = 128 rows * 5 k
        if (idx < 128 * KT) {
            const int row = idx / KT, k = idx % KT;
            float S = 0.f, Q = 0.f, G = 0.f;
#pragma unroll
            for (int q = 0; q < 4; ++q) {
                const float* sp_ = scr + ((q * 128 + row) * KT + k) * 3;
                S += sp_[0];
                Q += sp_[1];
                G += sp_[2];
            }
            float4 o;
            o.x = S;
            o.y = Q;
            o.z = G;
            o.w = 0.f;
            *(float4*)(part + (((size_t)bn * (BB * SS) + row0 + row) * KT + k) * 4) = o;
        }
    }
}

// ---------------- K7 final: epi2+softmax_end fused (80) | ansred (16) ----------------
__global__ void k_final(const float* __restrict__ part, const float* __restrict__ p_mask,
                        const float* __restrict__ scal, const float* __restrict__ b_end1,
                        const float* __restrict__ anspart, const float* __restrict__ b_ans0,
                        const float* __restrict__ w_ans1, float* __restrict__ out) {
    const int bid = blockIdx.x;
    const int t = threadIdx.x;
    __shared__ float rscr[4];

    if (bid < 80) {
        // ---- epi2 (compute masked end logits for this (b,k)) + softmax + top-5 ----
        const int b = bid / KT, k = bid % KT;
        const float GW1 = scal[0], BW1 = scal[1], be1 = b_end1[0];
        float x01[2];
#pragma unroll
        for (int h = 0; h < 2; ++h) {
            const int s = h * 256 + t;
            const int row = b * SS + s;
            float S = 0.f, Q = 0.f, G = 0.f;
#pragma unroll
            for (int bn = 0; bn < 8; ++bn) {
                float4 v = *(const float4*)(part + (((size_t)bn * (BB * SS) + row) * KT + k) * 4);
                S += v.x;
                Q += v.y;
                G += v.z;
            }
            const float mu = S * (1.f / HH);
            const float var = Q * (1.f / HH) - mu * mu;
            const float rs = rsqrtf(var + 1e-12f);
            const float logit = rs * (G - mu * GW1) + BW1 + be1;
            const float pm = p_mask[row];
            x01[h] = logit * (1.f - pm) - NEGV * pm;
        }
        softmax_topk_vals<false>(x01[0], x01[1], nullptr,
                                 out + 160 + b * 25 + k * KT, out + 560 + b * 25 + k * KT, nullptr);
    } else {
        // ---- ansred: cls_logits ----
        const int b = bid - 80;
        float dsum = 0.f;
#pragma unroll
        for (int q = 0; q < 4; ++q) {
            const int h = q * 256 + t;
            float s = b_ans0[h];
#pragma unroll
            for (int kc = 0; kc < 16; ++kc) s += anspart[((size_t)kc * 16 + b) * HH + h];
            dsum += tanhf(s) * w_ans1[h];
        }
        dsum = wave_sum(dsum);
        if ((t & 63) == 0) rscr[t >> 6] = dsum;
        __syncthreads();
        if (t == 0) out[960 + b] = rscr[0] + rscr[1] + rscr[2] + rscr[3];
    }
}

// ---------------- launch ----------------
extern "C" void kernel_launch(void* const* d_in, const int* in_sizes, int n_in,
                              void* d_out, int out_size, void* d_ws, size_t ws_size,
                              hipStream_t stream) {
    const float* seq     = (const float*)d_in[0];
    const float* p_mask  = (const float*)d_in[1];
    const float* w_start = (const float*)d_in[2];
    const float* b_start = (const float*)d_in[3];
    const float* w_end0  = (const float*)d_in[4];
    const float* b_end0  = (const float*)d_in[5];
    const float* ln_g    = (const float*)d_in[6];
    const float* ln_b    = (const float*)d_in[7];
    const float* w_end1  = (const float*)d_in[8];
    const float* b_end1  = (const float*)d_in[9];
    const float* w_ans0  = (const float*)d_in[10];
    const float* b_ans0  = (const float*)d_in[11];
    const float* w_ans1  = (const float*)d_in[12];
    float* out = (float*)d_out;

    float* sm      = (float*)d_ws;                  // 8192
    float* sp      = sm + BB * SS;                  // 8192
    float* partial = sp + BB * SS;                  // 524288
    float* feat    = partial + BB * 32 * HH;        // 32768
    float* Cb      = feat + BB * 2048;              // 81920
    float* Cpart   = Cb + 80 * HH;                  // 655360
    float* anspart = Cpart + 8 * 80 * HH;           // 262144
    float* scal    = anspart + 16 * BB * HH;        // 16
    int*   idx     = (int*)(scal + 16);             // 80
    float* part    = (float*)(((uintptr_t)(idx + 80) + 255) & ~(uintptr_t)255);  // 1310720 floats
    short* wpk_hi  = (short*)(part + 8 * BB * SS * KT * 4);
    short* wpk_lo  = wpk_hi + (1 << 20);            // 1M bf16 each
    short* apk_hi  = wpk_lo + (1 << 20);            // 8M bf16 each
    short* apk_lo  = apk_hi + (1 << 23);

    hipLaunchKernelGGL(k_mega, dim3(6657), dim3(256), 0, stream,
                       seq, w_end0, p_mask, w_start, b_start, ln_g, ln_b, w_end1,
                       wpk_hi, wpk_lo, apk_hi, apk_lo, sm, scal);
    hipLaunchKernelGGL(k_softmax_start, dim3(BB), dim3(256), 0, stream, sm, sp, out, idx);
    hipLaunchKernelGGL(k_mid, dim3(1024), dim3(256), 0, stream,
                       seq, idx, w_end0, Cpart, sp, partial);
    hipLaunchKernelGGL(k_red, dim3(96), dim3(256), 0, stream,
                       Cpart, b_end0, Cb, seq, partial, feat);
    hipLaunchKernelGGL(k_ans, dim3(1024), dim3(256), 0, stream, feat, w_ans0, anspart);
    hipLaunchKernelGGL(k_gemm, dim3(512), dim3(512), 65536, stream,
                       apk_hi, apk_lo, wpk_hi, wpk_lo, Cb, ln_g, w_end1, part);
    hipLaunchKernelGGL(k_final, dim3(96), dim3(256), 0, stream,
                       part, p_mask, scal, b_end1, anspart, b_ans0, w_ans1, out);
}

// Round 12
// 135.851 us; speedup vs baseline: 1.1005x; 1.1005x over previous
//
#include <hip/hip_runtime.h>
#include <math.h>

#define BB 16
#define SS 512
#define HH 1024
#define KT 5
#define NEGV 1e30f

typedef __attribute__((ext_vector_type(8))) short short8_t;
typedef __attribute__((ext_vector_type(4))) float f32x4;

// ---------------- helpers ----------------
__device__ __forceinline__ float wave_sum(float v) {
    for (int off = 32; off; off >>= 1) v += __shfl_down(v, off);
    return v;
}

__device__ __forceinline__ unsigned short bf16rn(float x) {
    unsigned u = __float_as_uint(x);
    return (unsigned short)((u + 0x7fffu + ((u >> 16) & 1u)) >> 16);
}

__device__ __forceinline__ void split2(float x, unsigned short& h, unsigned short& l) {
    h = bf16rn(x);
    float hf = __uint_as_float(((unsigned)h) << 16);
    l = bf16rn(x - hf);
}

__device__ __forceinline__ float tanh_fast(float x) {
    float e = __expf(2.0f * x);
    return 1.0f - 2.0f * __builtin_amdgcn_rcpf(e + 1.0f);
}

// async global->LDS, 16B per lane; lds dst must be wave-uniform base
__device__ __forceinline__ void gld16(const void* g, char* l) {
    __builtin_amdgcn_global_load_lds((const __attribute__((address_space(1))) void*)g,
                                     (__attribute__((address_space(3))) void*)l, 16, 0, 0);
}

// ---------------- softmax + top-5 over 512 values held as (x0,x1) per thread ----------------
template <bool WRITE_P>
__device__ void softmax_topk_vals(float x0, float x1, float* __restrict__ p_out,
                                  float* __restrict__ val_out, float* __restrict__ idxf_out,
                                  int* __restrict__ idxi_out) {
    const int t = threadIdx.x;
    __shared__ float scr[4];
    __shared__ float sv[4];
    __shared__ int si[4];
    __shared__ int wi_s;

    float m = fmaxf(x0, x1);
    for (int off = 32; off; off >>= 1) m = fmaxf(m, __shfl_down(m, off));
    if ((t & 63) == 0) scr[t >> 6] = m;
    __syncthreads();
    m = fmaxf(fmaxf(scr[0], scr[1]), fmaxf(scr[2], scr[3]));
    __syncthreads();

    float e0 = expf(x0 - m), e1 = expf(x1 - m);
    float ssum = wave_sum(e0 + e1);
    if ((t & 63) == 0) scr[t >> 6] = ssum;
    __syncthreads();
    ssum = scr[0] + scr[1] + scr[2] + scr[3];
    __syncthreads();

    if (WRITE_P) {
        p_out[t] = e0 / ssum;
        p_out[t + 256] = e1 / ssum;
    }
    const float lse = m + logf(ssum);

    float v0 = x0, v1 = x1;
    for (int k = 0; k < KT; ++k) {
        float bv;
        int bi;
        if (v0 >= v1) { bv = v0; bi = t; } else { bv = v1; bi = t + 256; }
        for (int off = 32; off; off >>= 1) {
            float ov = __shfl_down(bv, off);
            int oi = __shfl_down(bi, off);
            if (ov > bv || (ov == bv && oi < bi)) { bv = ov; bi = oi; }
        }
        if ((t & 63) == 0) { sv[t >> 6] = bv; si[t >> 6] = bi; }
        __syncthreads();
        if (t == 0) {
            float fv = sv[0];
            int fi = si[0];
            for (int w = 1; w < 4; ++w)
                if (sv[w] > fv || (sv[w] == fv && si[w] < fi)) { fv = sv[w]; fi = si[w]; }
            wi_s = fi;
            val_out[k] = fv - lse;
            idxf_out[k] = (float)fi;
            if (idxi_out) idxi_out[k] = fi;
        }
        __syncthreads();
        const int wi = wi_s;
        if (wi == t) v0 = -INFINITY;
        else if (wi == t + 256) v1 = -INFINITY;
        __syncthreads();
    }
}

// ---------------- K1 mega_prep: prep | start_logits | scal ----------------
// grid = 512 (prep) + 2048 (start_logits) + 1 (scal) = 2561
__global__ void k_mega(const float* __restrict__ seq, const float* __restrict__ w_end0,
                       const float* __restrict__ pm, const float* __restrict__ w_start,
                       const float* __restrict__ b_start, const float* __restrict__ ln_g,
                       const float* __restrict__ ln_b, const float* __restrict__ w_end1,
                       short* __restrict__ wpk_hi, short* __restrict__ wpk_lo,
                       float* __restrict__ sm, float* __restrict__ scal) {
    const int bid = blockIdx.x;
    const int t = threadIdx.x;
    __shared__ float scr8[8];

    if (bid < 512) {
        // ---- prep: pack W0a into MFMA B-frag order (bf16 hi/lo) ----
        const int nt = bid & 63;
        const int yy = bid >> 6;
        const int n_idx = t & 15;
        const int g = (t >> 4) & 3;
        const int kq = t >> 6;
        const int kblk = yy * 4 + kq;
        const int k0 = kblk * 32 + g * 8;
        unsigned short hs[8], ls[8];
#pragma unroll
        for (int j = 0; j < 8; ++j) {
            float v = w_end0[(size_t)(k0 + j) * HH + nt * 16 + n_idx];
            split2(v, hs[j], ls[j]);
        }
        const size_t fi = (((size_t)nt * 32 + kblk) * 64 + (g * 16 + n_idx)) * 8;
        short8_t hv, lv;
#pragma unroll
        for (int j = 0; j < 8; ++j) { hv[j] = (short)hs[j]; lv[j] = (short)ls[j]; }
        *(short8_t*)(wpk_hi + fi) = hv;
        *(short8_t*)(wpk_lo + fi) = lv;
    } else if (bid < 2560) {
        // ---- start_logits: wave per row ----
        const int l = t & 63;
        const int row = (bid - 512) * 4 + (t >> 6);
        const float4* rp = (const float4*)(seq + (size_t)row * HH);
        const float4* wp = (const float4*)w_start;
        float d = 0.f;
#pragma unroll
        for (int q = 0; q < 4; ++q) {
            float4 a = rp[q * 64 + l];
            float4 w = wp[q * 64 + l];
            d += a.x * w.x + a.y * w.y + a.z * w.z + a.w * w.w;
        }
        d = wave_sum(d);
        if (l == 0) {
            float m = pm[row];
            sm[row] = (d + b_start[0]) * (1.f - m) - NEGV * m;
        }
    } else {
        // ---- scal: GW1 = sum g*w1, BW1 = sum b*w1 ----
        float4 g = ((const float4*)ln_g)[t];
        float4 w = ((const float4*)w_end1)[t];
        float4 b = ((const float4*)ln_b)[t];
        float gw = g.x * w.x + g.y * w.y + g.z * w.z + g.w * w.w;
        float bw = b.x * w.x + b.y * w.y + b.z * w.z + b.w * w.w;
        gw = wave_sum(gw);
        bw = wave_sum(bw);
        if ((t & 63) == 0) { scr8[t >> 6] = gw; scr8[4 + (t >> 6)] = bw; }
        __syncthreads();
        if (t == 0) {
            scal[0] = scr8[0] + scr8[1] + scr8[2] + scr8[3];
            scal[1] = scr8[4] + scr8[5] + scr8[6] + scr8[7];
        }
    }
}

// ---------------- K2: softmax_start (start top-5 + probs) ----------------
__global__ void k_softmax_start(const float* __restrict__ sm, float* __restrict__ sp,
                                float* __restrict__ dout, int* __restrict__ idx) {
    const int b = blockIdx.x;
    const int t = threadIdx.x;
    const float* x = sm + (size_t)b * SS;
    softmax_topk_vals<true>(x[t], x[t + 256], sp + (size_t)b * SS,
                            dout + b * KT, dout + 80 + b * KT, idx + b * KT);
}

// ---------------- K3 mid: cfeat (512 blocks) | sf_partial (512 blocks) ----------------
__global__ void k_mid(const float* __restrict__ seq, const int* __restrict__ idx,
                      const float* __restrict__ w_end0, float* __restrict__ Cpart,
                      const float* __restrict__ sp, float* __restrict__ partial) {
    __shared__ float shA[80 * 132];
    __shared__ float shW[16 * 132];
    __shared__ int growL[80];
    const int bid = blockIdx.x;
    const int t = threadIdx.x;

    if (bid < 512) {
        // ---- cfeat: Cb partials, K-split ----
        const int c = bid & 63;
        const int kc = bid >> 6;
        if (t < 80) growL[t] = (t / KT) * SS + idx[t];
        __syncthreads();
        for (int i = 0; i < 40; ++i) {
            const int e = i * 256 + t;
            const int r = e >> 7, d = e & 127;
            shA[r * 132 + d] = seq[(size_t)growL[r] * HH + kc * 128 + d];
        }
#pragma unroll
        for (int p = 0; p < 8; ++p) {
            const int e = p * 256 + t;
            const int d = e >> 4, j = e & 15;
            shW[j * 132 + d] = w_end0[(size_t)(HH + kc * 128 + d) * HH + c * 16 + j];
        }
        __syncthreads();
        const int j = t & 15, rg = t >> 4;
        const float4* A4 = (const float4*)shA;
        const float4* W4 = (const float4*)shW;
        float acc[5] = {0.f, 0.f, 0.f, 0.f, 0.f};
        for (int d4 = 0; d4 < 32; ++d4) {
            float4 wv = W4[j * 33 + d4];
#pragma unroll
            for (int i = 0; i < 5; ++i) {
                float4 av = A4[(rg + 16 * i) * 33 + d4];
                acc[i] += av.x * wv.x + av.y * wv.y + av.z * wv.z + av.w * wv.w;
            }
        }
#pragma unroll
        for (int i = 0; i < 5; ++i)
            Cpart[((size_t)kc * 80 + rg + 16 * i) * HH + c * 16 + j] = acc[i];
    } else {
        // ---- sf_partial: start_feature partial sums (16-row chunks) ----
        const int bid2 = bid - 512;
        const int chunk = bid2 & 31;
        const int b = bid2 >> 5;
        if (t < 16) shA[t] = sp[b * SS + chunk * 16 + t];
        __syncthreads();
        float4 acc = make_float4(0.f, 0.f, 0.f, 0.f);
        const float4* base = (const float4*)(seq + ((size_t)b * SS + chunk * 16) * HH);
        for (int s = 0; s < 16; ++s) {
            float4 v = base[(size_t)s * 256 + t];
            float ps = shA[s];
            acc.x = fmaf(ps, v.x, acc.x);
            acc.y = fmaf(ps, v.y, acc.y);
            acc.z = fmaf(ps, v.z, acc.z);
            acc.w = fmaf(ps, v.w, acc.w);
        }
        ((float4*)partial)[(size_t)(b * 32 + chunk) * 256 + t] = acc;
    }
}

// ---------------- K4 red: cbred (80) | featsum (16) ----------------
__global__ void k_red(const float* __restrict__ Cpart, const float* __restrict__ b_end0,
                      float* __restrict__ Cb, const float* __restrict__ seq,
                      const float* __restrict__ partial, float* __restrict__ feat) {
    const int bid = blockIdx.x;
    const int t = threadIdx.x;
    if (bid < 80) {
        const int bk = bid;
#pragma unroll
        for (int q = 0; q < 4; ++q) {
            const int h = q * 256 + t;
            float s = b_end0[h];
#pragma unroll
            for (int kc = 0; kc < 8; ++kc) s += Cpart[((size_t)kc * 80 + bk) * HH + h];
            Cb[(size_t)bk * HH + h] = s;
        }
    } else {
        const int b = bid - 80;
        for (int q = 0; q < 4; ++q) {
            const int h = q * 256 + t;
            float s = 0.f;
            for (int c = 0; c < 32; ++c) s += partial[(size_t)(b * 32 + c) * HH + h];
            feat[(size_t)b * 2048 + h] = s;
            feat[(size_t)b * 2048 + HH + h] = seq[(size_t)b * SS * HH + h];
        }
    }
}

// ---------------- K5: ans-head GEMM partials, K-split (1024 blocks) ----------------
__global__ void k_ans(const float* __restrict__ feat, const float* __restrict__ w_ans0,
                      float* __restrict__ anspart) {
    __shared__ float A[16 * 132];
    __shared__ float W[16 * 132];
    const int c = blockIdx.x & 63;
    const int kc = blockIdx.x >> 6;
    const int t = threadIdx.x;
#pragma unroll
    for (int i = 0; i < 8; ++i) {
        const int e = i * 256 + t;
        const int b = e >> 7, d = e & 127;
        A[b * 132 + d] = feat[(size_t)b * 2048 + kc * 128 + d];
    }
#pragma unroll
    for (int p = 0; p < 8; ++p) {
        const int e = p * 256 + t;
        const int d = e >> 4, j = e & 15;
        W[j * 132 + d] = w_ans0[(size_t)(kc * 128 + d) * HH + c * 16 + j];
    }
    __syncthreads();
    const int j = t & 15, b = t >> 4;
    const float4* A4 = (const float4*)A;
    const float4* W4 = (const float4*)W;
    float acc = 0.f;
    for (int d4 = 0; d4 < 32; ++d4) {
        float4 wv = W4[j * 33 + d4];
        float4 av = A4[b * 33 + d4];
        acc += av.x * wv.x + av.y * wv.y + av.z * wv.z + av.w * wv.w;
    }
    anspart[((size_t)kc * 16 + b) * HH + c * 16 + j] = acc;
}

// ---------------- K6 k_gemm: split-bf16 MFMA GEMM, raw-seq A with in-reg split ----------------
// BM=128 x BN=128, BK=32, 4 waves (2x2), wave tile 64x64 (R6 proven skeleton).
// A staged as raw f32 seq rows via global_load_lds with G4 row-XOR swizzle
// (chunk c at row r lives at physical chunk c^(r&7); DMA source pre-swizzled,
// ds_read applies the same XOR). bf16 hi/lo split done in-register (bitwise
// identical to the old seqpk). W from pre-packed wpk hi/lo as before.
// Per buffer (32 KB): A f32 [128][32] swizzled @0 (16KB), WH @16K, WL @24K.
// XCD swizzle: each XCD owns an 8bm x 8bn square region.
__global__ __launch_bounds__(256, 2)
void k_gemm(const float* __restrict__ seq, const short* __restrict__ wpk_hi,
            const short* __restrict__ wpk_lo, const float* __restrict__ Cb,
            const float* __restrict__ ln_g, const float* __restrict__ w_end1,
            float* __restrict__ part) {
    extern __shared__ char smem[];  // 65536
    const int t = threadIdx.x;
    const int l = t & 63, w = t >> 6;
    const int wr = w >> 1, wc = w & 1;
    const int wg = blockIdx.x;
    const int xcd = wg & 7;
    const int local = wg >> 3;          // 0..63
    const int bm = xcd * 8 + (local >> 3);
    const int bn = local & 7;
    const int row0 = bm * 128;
    const int b = row0 >> 9;

    f32x4 acc[4][4];
#pragma unroll
    for (int m = 0; m < 4; ++m)
#pragma unroll
        for (int n = 0; n < 4; ++n) acc[m][n] = (f32x4){0.f, 0.f, 0.f, 0.f};

    // ---- precomputed staging addresses ----
    // A: 1024 chunks of 16B per buffer; chunk i: row=i>>3, phys c=i&7,
    // logical c = (i&7)^(row&7); src = seq[row0+row][ks*32 + c*4].
    const float* asrc[4];
    int adst[4];
#pragma unroll
    for (int q = 0; q < 4; ++q) {
        const int i = w * 256 + q * 64 + l;
        const int row = i >> 3;
        const int c = (i & 7) ^ (row & 7);
        asrc[q] = seq + ((size_t)(row0 + row) << 10) + c * 4;
        adst[q] = i * 16;
    }
    const short* wsrc_hi[2];
    const short* wsrc_lo[2];
    int wdst[2];
#pragma unroll
    for (int q = 0; q < 2; ++q) {
        const int fr = w + q * 4;
        wsrc_hi[q] = wpk_hi + ((size_t)(bn * 8 + fr) * 32) * 512 + l * 8;
        wsrc_lo[q] = wpk_lo + ((size_t)(bn * 8 + fr) * 32) * 512 + l * 8;
        wdst[q] = fr * 1024;
    }

#define STAGE(buf, ks)                                                     \
    {                                                                      \
        char* lb = smem + (buf) * 32768;                                   \
        _Pragma("unroll") for (int q = 0; q < 4; ++q)                      \
            gld16(asrc[q] + (ks) * 32, lb + adst[q]);                      \
        _Pragma("unroll") for (int q = 0; q < 2; ++q) {                    \
            gld16(wsrc_hi[q] + (ks) * 512, lb + 16384 + wdst[q]);          \
            gld16(wsrc_lo[q] + (ks) * 512, lb + 24576 + wdst[q]);          \
        }                                                                  \
    }

    STAGE(0, 0);
    __syncthreads();

    // per-thread A-read constants
    const int c0 = (l >> 4) << 1;  // first logical chunk of this lane's k-group

    for (int ks = 0; ks < 32; ++ks) {
        const int buf = ks & 1;
        if (ks < 31) STAGE(buf ^ 1, ks + 1);
        {
            const char* base_ = smem + buf * 32768;
            short8_t ah[4], al[4], wh[4], wl[4];
#pragma unroll
            for (int m = 0; m < 4; ++m) {
                const int rowm = (wr * 4 + m) * 16 + (l & 15);
                const int rb = rowm * 128;
                const int sw = (rowm & 7) << 4;
                float4 a0 = *(const float4*)(base_ + rb + ((c0 << 4) ^ sw));
                float4 a1 = *(const float4*)(base_ + rb + (((c0 + 1) << 4) ^ sw));
                unsigned short h0, g0, h1, g1, h2, g2, h3, g3, h4, g4, h5, g5, h6, g6, h7, g7;
                split2(a0.x, h0, g0);
                split2(a0.y, h1, g1);
                split2(a0.z, h2, g2);
                split2(a0.w, h3, g3);
                split2(a1.x, h4, g4);
                split2(a1.y, h5, g5);
                split2(a1.z, h6, g6);
                split2(a1.w, h7, g7);
                short8_t hv, lv;
                hv[0] = (short)h0; hv[1] = (short)h1; hv[2] = (short)h2; hv[3] = (short)h3;
                hv[4] = (short)h4; hv[5] = (short)h5; hv[6] = (short)h6; hv[7] = (short)h7;
                lv[0] = (short)g0; lv[1] = (short)g1; lv[2] = (short)g2; lv[3] = (short)g3;
                lv[4] = (short)g4; lv[5] = (short)g5; lv[6] = (short)g6; lv[7] = (short)g7;
                ah[m] = hv;
                al[m] = lv;
            }
#pragma unroll
            for (int n = 0; n < 4; ++n) {
                const int ntl = wc * 4 + n;
                wh[n] = *(const short8_t*)(base_ + 16384 + (ntl << 10) + (l << 4));
                wl[n] = *(const short8_t*)(base_ + 24576 + (ntl << 10) + (l << 4));
            }
            __builtin_amdgcn_s_setprio(1);
#pragma unroll
            for (int n = 0; n < 4; ++n)
#pragma unroll
                for (int m = 0; m < 4; ++m) {
                    acc[m][n] = __builtin_amdgcn_mfma_f32_16x16x32_bf16(ah[m], wh[n], acc[m][n], 0, 0, 0);
                    acc[m][n] = __builtin_amdgcn_mfma_f32_16x16x32_bf16(al[m], wh[n], acc[m][n], 0, 0, 0);
                    acc[m][n] = __builtin_amdgcn_mfma_f32_16x16x32_bf16(ah[m], wl[n], acc[m][n], 0, 0, 0);
                }
            __builtin_amdgcn_s_setprio(0);
        }
        __syncthreads();
    }
#undef STAGE

    // ---- epilogue: per-block partial (S,Q,G) over this 128-col slice ----
    float cbv[KT][4], gwv[4];
#pragma unroll
    for (int n = 0; n < 4; ++n) {
        const int col = bn * 128 + wc * 64 + n * 16 + (l & 15);
        gwv[n] = ln_g[col] * w_end1[col];
#pragma unroll
        for (int k = 0; k < KT; ++k) cbv[k][n] = Cb[(size_t)(b * KT + k) * HH + col];
    }
    float* scr = (float*)smem;  // [wc 2][row 128][k 5][3]

    for (int k = 0; k < KT; ++k) {
        float S[4][4], Q[4][4], G[4][4];
#pragma unroll
        for (int m = 0; m < 4; ++m)
#pragma unroll
            for (int r = 0; r < 4; ++r) { S[m][r] = 0.f; Q[m][r] = 0.f; G[m][r] = 0.f; }
#pragma unroll
        for (int n = 0; n < 4; ++n) {
            const float cb = cbv[k][n];
            const float gwn = gwv[n];
#pragma unroll
            for (int m = 0; m < 4; ++m)
#pragma unroll
                for (int r = 0; r < 4; ++r) {
                    float v = tanh_fast(acc[m][n][r] + cb);
                    S[m][r] += v;
                    Q[m][r] += v * v;
                    G[m][r] += v * gwn;
                }
        }
        for (int msk = 1; msk < 16; msk <<= 1) {
#pragma unroll
            for (int m = 0; m < 4; ++m)
#pragma unroll
                for (int r = 0; r < 4; ++r) {
                    S[m][r] += __shfl_xor(S[m][r], msk);
                    Q[m][r] += __shfl_xor(Q[m][r], msk);
                    G[m][r] += __shfl_xor(G[m][r], msk);
                }
        }
        if ((l & 15) == 0) {
            const int gg = l >> 4;
#pragma unroll
            for (int m = 0; m < 4; ++m)
#pragma unroll
                for (int r = 0; r < 4; ++r) {
                    const int row = wr * 64 + m * 16 + gg * 4 + r;
                    float* sp_ = scr + ((wc * 128 + row) * KT + k) * 3;
                    sp_[0] = S[m][r];
                    sp_[1] = Q[m][r];
                    sp_[2] = G[m][r];
                }
        }
    }
    __syncthreads();

#pragma unroll
    for (int i = 0; i < 3; ++i) {
        const int idx = i * 256 + t;  // 640 = 128 rows * 5 k
        if (idx < 128 * KT) {
            const int row = idx / KT, k = idx % KT;
            const float* a_ = scr + ((0 * 128 + row) * KT + k) * 3;
            const float* b_ = scr + ((1 * 128 + row) * KT + k) * 3;
            float4 o;
            o.x = a_[0] + b_[0];
            o.y = a_[1] + b_[1];
            o.z = a_[2] + b_[2];
            o.w = 0.f;
            *(float4*)(part + (((size_t)bn * (BB * SS) + row0 + row) * KT + k) * 4) = o;
        }
    }
}

// ---------------- K7 final: epi2+softmax_end fused (80) | ansred (16) ----------------
__global__ void k_final(const float* __restrict__ part, const float* __restrict__ p_mask,
                        const float* __restrict__ scal, const float* __restrict__ b_end1,
                        const float* __restrict__ anspart, const float* __restrict__ b_ans0,
                        const float* __restrict__ w_ans1, float* __restrict__ out) {
    const int bid = blockIdx.x;
    const int t = threadIdx.x;
    __shared__ float rscr[4];

    if (bid < 80) {
        // ---- epi2 (compute masked end logits for this (b,k)) + softmax + top-5 ----
        const int b = bid / KT, k = bid % KT;
        const float GW1 = scal[0], BW1 = scal[1], be1 = b_end1[0];
        float x01[2];
#pragma unroll
        for (int h = 0; h < 2; ++h) {
            const int s = h * 256 + t;
            const int row = b * SS + s;
            float S = 0.f, Q = 0.f, G = 0.f;
#pragma unroll
            for (int bn = 0; bn < 8; ++bn) {
                float4 v = *(const float4*)(part + (((size_t)bn * (BB * SS) + row) * KT + k) * 4);
                S += v.x;
                Q += v.y;
                G += v.z;
            }
            const float mu = S * (1.f / HH);
            const float var = Q * (1.f / HH) - mu * mu;
            const float rs = rsqrtf(var + 1e-12f);
            const float logit = rs * (G - mu * GW1) + BW1 + be1;
            const float pm = p_mask[row];
            x01[h] = logit * (1.f - pm) - NEGV * pm;
        }
        softmax_topk_vals<false>(x01[0], x01[1], nullptr,
                                 out + 160 + b * 25 + k * KT, out + 560 + b * 25 + k * KT, nullptr);
    } else {
        // ---- ansred: cls_logits ----
        const int b = bid - 80;
        float dsum = 0.f;
#pragma unroll
        for (int q = 0; q < 4; ++q) {
            const int h = q * 256 + t;
            float s = b_ans0[h];
#pragma unroll
            for (int kc = 0; kc < 16; ++kc) s += anspart[((size_t)kc * 16 + b) * HH + h];
            dsum += tanhf(s) * w_ans1[h];
        }
        dsum = wave_sum(dsum);
        if ((t & 63) == 0) rscr[t >> 6] = dsum;
        __syncthreads();
        if (t == 0) out[960 + b] = rscr[0] + rscr[1] + rscr[2] + rscr[3];
    }
}

// ---------------- launch ----------------
extern "C" void kernel_launch(void* const* d_in, const int* in_sizes, int n_in,
                              void* d_out, int out_size, void* d_ws, size_t ws_size,
                              hipStream_t stream) {
    const float* seq     = (const float*)d_in[0];
    const float* p_mask  = (const float*)d_in[1];
    const float* w_start = (const float*)d_in[2];
    const float* b_start = (const float*)d_in[3];
    const float* w_end0  = (const float*)d_in[4];
    const float* b_end0  = (const float*)d_in[5];
    const float* ln_g    = (const float*)d_in[6];
    const float* ln_b    = (const float*)d_in[7];
    const float* w_end1  = (const float*)d_in[8];
    const float* b_end1  = (const float*)d_in[9];
    const float* w_ans0  = (const float*)d_in[10];
    const float* b_ans0  = (const float*)d_in[11];
    const float* w_ans1  = (const float*)d_in[12];
    float* out = (float*)d_out;

    float* sm      = (float*)d_ws;                  // 8192
    float* sp      = sm + BB * SS;                  // 8192
    float* partial = sp + BB * SS;                  // 524288
    float* feat    = partial + BB * 32 * HH;        // 32768
    float* Cb      = feat + BB * 2048;              // 81920
    float* Cpart   = Cb + 80 * HH;                  // 655360
    float* anspart = Cpart + 8 * 80 * HH;           // 262144
    float* scal    = anspart + 16 * BB * HH;        // 16
    int*   idx     = (int*)(scal + 16);             // 80
    float* part    = (float*)(((uintptr_t)(idx + 80) + 255) & ~(uintptr_t)255);  // 1310720 floats
    short* wpk_hi  = (short*)(part + 8 * BB * SS * KT * 4);
    short* wpk_lo  = wpk_hi + (1 << 20);            // 1M bf16 each

    hipLaunchKernelGGL(k_mega, dim3(2561), dim3(256), 0, stream,
                       seq, w_end0, p_mask, w_start, b_start, ln_g, ln_b, w_end1,
                       wpk_hi, wpk_lo, sm, scal);
    hipLaunchKernelGGL(k_softmax_start, dim3(BB), dim3(256), 0, stream, sm, sp, out, idx);
    hipLaunchKernelGGL(k_mid, dim3(1024), dim3(256), 0, stream,
                       seq, idx, w_end0, Cpart, sp, partial);
    hipLaunchKernelGGL(k_red, dim3(96), dim3(256), 0, stream,
                       Cpart, b_end0, Cb, seq, partial, feat);
    hipLaunchKernelGGL(k_ans, dim3(1024), dim3(256), 0, stream, feat, w_ans0, anspart);
    hipLaunchKernelGGL(k_gemm, dim3(512), dim3(256), 65536, stream,
                       seq, wpk_hi, wpk_lo, Cb, ln_g, w_end1, part);
    hipLaunchKernelGGL(k_final, dim3(96), dim3(256), 0, stream,
                       part, p_mask, scal, b_end1, anspart, b_ans0, w_ans1, out);
}

// Round 13
// 130.934 us; speedup vs baseline: 1.1419x; 1.0376x over previous
//
#include <hip/hip_runtime.h>
#include <math.h>

#define BB 16
#define SS 512
#define HH 1024
#define KT 5
#define NEGV 1e30f

typedef __attribute__((ext_vector_type(8))) short short8_t;
typedef __attribute__((ext_vector_type(4))) float f32x4;

// ---------------- helpers ----------------
__device__ __forceinline__ float wave_sum(float v) {
    for (int off = 32; off; off >>= 1) v += __shfl_down(v, off);
    return v;
}

__device__ __forceinline__ unsigned short bf16rn(float x) {
    unsigned u = __float_as_uint(x);
    return (unsigned short)((u + 0x7fffu + ((u >> 16) & 1u)) >> 16);
}

__device__ __forceinline__ void split2(float x, unsigned short& h, unsigned short& l) {
    h = bf16rn(x);
    float hf = __uint_as_float(((unsigned)h) << 16);
    l = bf16rn(x - hf);
}

__device__ __forceinline__ float tanh_fast(float x) {
    float e = __expf(2.0f * x);
    return 1.0f - 2.0f * __builtin_amdgcn_rcpf(e + 1.0f);
}

// async global->LDS, 16B per lane; lds dst must be wave-uniform base
__device__ __forceinline__ void gld16(const void* g, char* l) {
    __builtin_amdgcn_global_load_lds((const __attribute__((address_space(1))) void*)g,
                                     (__attribute__((address_space(3))) void*)l, 16, 0, 0);
}

// ---------------- softmax + top-5 over 512 values held as (x0,x1) per thread ----------------
template <bool WRITE_P>
__device__ void softmax_topk_vals(float x0, float x1, float* __restrict__ p_out,
                                  float* __restrict__ val_out, float* __restrict__ idxf_out,
                                  int* __restrict__ idxi_out) {
    const int t = threadIdx.x;
    __shared__ float scr[4];
    __shared__ float sv[4];
    __shared__ int si[4];
    __shared__ int wi_s;

    float m = fmaxf(x0, x1);
    for (int off = 32; off; off >>= 1) m = fmaxf(m, __shfl_down(m, off));
    if ((t & 63) == 0) scr[t >> 6] = m;
    __syncthreads();
    m = fmaxf(fmaxf(scr[0], scr[1]), fmaxf(scr[2], scr[3]));
    __syncthreads();

    float e0 = expf(x0 - m), e1 = expf(x1 - m);
    float ssum = wave_sum(e0 + e1);
    if ((t & 63) == 0) scr[t >> 6] = ssum;
    __syncthreads();
    ssum = scr[0] + scr[1] + scr[2] + scr[3];
    __syncthreads();

    if (WRITE_P) {
        p_out[t] = e0 / ssum;
        p_out[t + 256] = e1 / ssum;
    }
    const float lse = m + logf(ssum);

    float v0 = x0, v1 = x1;
    for (int k = 0; k < KT; ++k) {
        float bv;
        int bi;
        if (v0 >= v1) { bv = v0; bi = t; } else { bv = v1; bi = t + 256; }
        for (int off = 32; off; off >>= 1) {
            float ov = __shfl_down(bv, off);
            int oi = __shfl_down(bi, off);
            if (ov > bv || (ov == bv && oi < bi)) { bv = ov; bi = oi; }
        }
        if ((t & 63) == 0) { sv[t >> 6] = bv; si[t >> 6] = bi; }
        __syncthreads();
        if (t == 0) {
            float fv = sv[0];
            int fi = si[0];
            for (int w = 1; w < 4; ++w)
                if (sv[w] > fv || (sv[w] == fv && si[w] < fi)) { fv = sv[w]; fi = si[w]; }
            wi_s = fi;
            val_out[k] = fv - lse;
            idxf_out[k] = (float)fi;
            if (idxi_out) idxi_out[k] = fi;
        }
        __syncthreads();
        const int wi = wi_s;
        if (wi == t) v0 = -INFINITY;
        else if (wi == t + 256) v1 = -INFINITY;
        __syncthreads();
    }
}

// ---------------- K1 mega_prep: seqpk | prep | start_logits | scal ----------------
// grid = 4096 (seqpk) + 512 (prep) + 2048 (start_logits) + 1 (scal) = 6657
__global__ void k_mega(const float* __restrict__ seq, const float* __restrict__ w_end0,
                       const float* __restrict__ pm, const float* __restrict__ w_start,
                       const float* __restrict__ b_start, const float* __restrict__ ln_g,
                       const float* __restrict__ ln_b, const float* __restrict__ w_end1,
                       short* __restrict__ wpk_hi, short* __restrict__ wpk_lo,
                       short* __restrict__ apk_hi, short* __restrict__ apk_lo,
                       float* __restrict__ sm, float* __restrict__ scal) {
    const int bid = blockIdx.x;
    const int t = threadIdx.x;
    __shared__ float scr8[8];

    if (bid < 4096) {
        // ---- seqpk: pack seq into MFMA A-frag order (bf16 hi/lo) ----
        // Apk layout: [bm(64)][ks(32)][mtl(8)][lane(64)][8] bf16
        const size_t g = (size_t)bid * 256 + t;
        const int l = g & 63;
        const int mtl = (g >> 6) & 7;
        const int ks = (g >> 9) & 31;
        const int bm = g >> 14;
        const int row = bm * 128 + mtl * 16 + (l & 15);
        const int k0 = ks * 32 + (l >> 4) * 8;
        const float4 v0 = *(const float4*)(seq + (size_t)row * HH + k0);
        const float4 v1 = *(const float4*)(seq + (size_t)row * HH + k0 + 4);
        float xs[8] = {v0.x, v0.y, v0.z, v0.w, v1.x, v1.y, v1.z, v1.w};
        unsigned short h[8], lo[8];
#pragma unroll
        for (int j = 0; j < 8; ++j) split2(xs[j], h[j], lo[j]);
        short8_t hv, lv;
#pragma unroll
        for (int j = 0; j < 8; ++j) { hv[j] = (short)h[j]; lv[j] = (short)lo[j]; }
        *(short8_t*)(apk_hi + g * 8) = hv;
        *(short8_t*)(apk_lo + g * 8) = lv;
    } else if (bid < 4608) {
        // ---- prep: pack W0a into MFMA B-frag order (bf16 hi/lo) ----
        const int bid2 = bid - 4096;
        const int nt = bid2 & 63;
        const int yy = bid2 >> 6;
        const int n_idx = t & 15;
        const int g = (t >> 4) & 3;
        const int kq = t >> 6;
        const int kblk = yy * 4 + kq;
        const int k0 = kblk * 32 + g * 8;
        unsigned short hs[8], ls[8];
#pragma unroll
        for (int j = 0; j < 8; ++j) {
            float v = w_end0[(size_t)(k0 + j) * HH + nt * 16 + n_idx];
            split2(v, hs[j], ls[j]);
        }
        const size_t fi = (((size_t)nt * 32 + kblk) * 64 + (g * 16 + n_idx)) * 8;
        short8_t hv, lv;
#pragma unroll
        for (int j = 0; j < 8; ++j) { hv[j] = (short)hs[j]; lv[j] = (short)ls[j]; }
        *(short8_t*)(wpk_hi + fi) = hv;
        *(short8_t*)(wpk_lo + fi) = lv;
    } else if (bid < 6656) {
        // ---- start_logits: wave per row ----
        const int l = t & 63;
        const int row = (bid - 4608) * 4 + (t >> 6);
        const float4* rp = (const float4*)(seq + (size_t)row * HH);
        const float4* wp = (const float4*)w_start;
        float d = 0.f;
#pragma unroll
        for (int q = 0; q < 4; ++q) {
            float4 a = rp[q * 64 + l];
            float4 w = wp[q * 64 + l];
            d += a.x * w.x + a.y * w.y + a.z * w.z + a.w * w.w;
        }
        d = wave_sum(d);
        if (l == 0) {
            float m = pm[row];
            sm[row] = (d + b_start[0]) * (1.f - m) - NEGV * m;
        }
    } else {
        // ---- scal: GW1 = sum g*w1, BW1 = sum b*w1 ----
        float4 g = ((const float4*)ln_g)[t];
        float4 w = ((const float4*)w_end1)[t];
        float4 b = ((const float4*)ln_b)[t];
        float gw = g.x * w.x + g.y * w.y + g.z * w.z + g.w * w.w;
        float bw = b.x * w.x + b.y * w.y + b.z * w.z + b.w * w.w;
        gw = wave_sum(gw);
        bw = wave_sum(bw);
        if ((t & 63) == 0) { scr8[t >> 6] = gw; scr8[4 + (t >> 6)] = bw; }
        __syncthreads();
        if (t == 0) {
            scal[0] = scr8[0] + scr8[1] + scr8[2] + scr8[3];
            scal[1] = scr8[4] + scr8[5] + scr8[6] + scr8[7];
        }
    }
}

// ---------------- K2: softmax_start (start top-5 + probs) ----------------
__global__ void k_softmax_start(const float* __restrict__ sm, float* __restrict__ sp,
                                float* __restrict__ dout, int* __restrict__ idx) {
    const int b = blockIdx.x;
    const int t = threadIdx.x;
    const float* x = sm + (size_t)b * SS;
    softmax_topk_vals<true>(x[t], x[t + 256], sp + (size_t)b * SS,
                            dout + b * KT, dout + 80 + b * KT, idx + b * KT);
}

// ---------------- K3 mid: cfeat (512 blocks) | sf_partial (512 blocks) ----------------
__global__ void k_mid(const float* __restrict__ seq, const int* __restrict__ idx,
                      const float* __restrict__ w_end0, float* __restrict__ Cpart,
                      const float* __restrict__ sp, float* __restrict__ partial) {
    __shared__ float shA[80 * 132];
    __shared__ float shW[16 * 132];
    __shared__ int growL[80];
    const int bid = blockIdx.x;
    const int t = threadIdx.x;

    if (bid < 512) {
        // ---- cfeat: Cb partials, K-split ----
        const int c = bid & 63;
        const int kc = bid >> 6;
        if (t < 80) growL[t] = (t / KT) * SS + idx[t];
        __syncthreads();
        for (int i = 0; i < 40; ++i) {
            const int e = i * 256 + t;
            const int r = e >> 7, d = e & 127;
            shA[r * 132 + d] = seq[(size_t)growL[r] * HH + kc * 128 + d];
        }
#pragma unroll
        for (int p = 0; p < 8; ++p) {
            const int e = p * 256 + t;
            const int d = e >> 4, j = e & 15;
            shW[j * 132 + d] = w_end0[(size_t)(HH + kc * 128 + d) * HH + c * 16 + j];
        }
        __syncthreads();
        const int j = t & 15, rg = t >> 4;
        const float4* A4 = (const float4*)shA;
        const float4* W4 = (const float4*)shW;
        float acc[5] = {0.f, 0.f, 0.f, 0.f, 0.f};
        for (int d4 = 0; d4 < 32; ++d4) {
            float4 wv = W4[j * 33 + d4];
#pragma unroll
            for (int i = 0; i < 5; ++i) {
                float4 av = A4[(rg + 16 * i) * 33 + d4];
                acc[i] += av.x * wv.x + av.y * wv.y + av.z * wv.z + av.w * wv.w;
            }
        }
#pragma unroll
        for (int i = 0; i < 5; ++i)
            Cpart[((size_t)kc * 80 + rg + 16 * i) * HH + c * 16 + j] = acc[i];
    } else {
        // ---- sf_partial: start_feature partial sums (16-row chunks) ----
        const int bid2 = bid - 512;
        const int chunk = bid2 & 31;
        const int b = bid2 >> 5;
        if (t < 16) shA[t] = sp[b * SS + chunk * 16 + t];
        __syncthreads();
        float4 acc = make_float4(0.f, 0.f, 0.f, 0.f);
        const float4* base = (const float4*)(seq + ((size_t)b * SS + chunk * 16) * HH);
        for (int s = 0; s < 16; ++s) {
            float4 v = base[(size_t)s * 256 + t];
            float ps = shA[s];
            acc.x = fmaf(ps, v.x, acc.x);
            acc.y = fmaf(ps, v.y, acc.y);
            acc.z = fmaf(ps, v.z, acc.z);
            acc.w = fmaf(ps, v.w, acc.w);
        }
        ((float4*)partial)[(size_t)(b * 32 + chunk) * 256 + t] = acc;
    }
}

// ---------------- K4 red: cbred (80) | featsum (16) ----------------
__global__ void k_red(const float* __restrict__ Cpart, const float* __restrict__ b_end0,
                      float* __restrict__ Cb, const float* __restrict__ seq,
                      const float* __restrict__ partial, float* __restrict__ feat) {
    const int bid = blockIdx.x;
    const int t = threadIdx.x;
    if (bid < 80) {
        const int bk = bid;
#pragma unroll
        for (int q = 0; q < 4; ++q) {
            const int h = q * 256 + t;
            float s = b_end0[h];
#pragma unroll
            for (int kc = 0; kc < 8; ++kc) s += Cpart[((size_t)kc * 80 + bk) * HH + h];
            Cb[(size_t)bk * HH + h] = s;
        }
    } else {
        const int b = bid - 80;
        for (int q = 0; q < 4; ++q) {
            const int h = q * 256 + t;
            float s = 0.f;
            for (int c = 0; c < 32; ++c) s += partial[(size_t)(b * 32 + c) * HH + h];
            feat[(size_t)b * 2048 + h] = s;
            feat[(size_t)b * 2048 + HH + h] = seq[(size_t)b * SS * HH + h];
        }
    }
}

// ---------------- K5: ans-head GEMM partials, K-split (1024 blocks) ----------------
__global__ void k_ans(const float* __restrict__ feat, const float* __restrict__ w_ans0,
                      float* __restrict__ anspart) {
    __shared__ float A[16 * 132];
    __shared__ float W[16 * 132];
    const int c = blockIdx.x & 63;
    const int kc = blockIdx.x >> 6;
    const int t = threadIdx.x;
#pragma unroll
    for (int i = 0; i < 8; ++i) {
        const int e = i * 256 + t;
        const int b = e >> 7, d = e & 127;
        A[b * 132 + d] = feat[(size_t)b * 2048 + kc * 128 + d];
    }
#pragma unroll
    for (int p = 0; p < 8; ++p) {
        const int e = p * 256 + t;
        const int d = e >> 4, j = e & 15;
        W[j * 132 + d] = w_ans0[(size_t)(kc * 128 + d) * HH + c * 16 + j];
    }
    __syncthreads();
    const int j = t & 15, b = t >> 4;
    const float4* A4 = (const float4*)A;
    const float4* W4 = (const float4*)W;
    float acc = 0.f;
    for (int d4 = 0; d4 < 32; ++d4) {
        float4 wv = W4[j * 33 + d4];
        float4 av = A4[b * 33 + d4];
        acc += av.x * wv.x + av.y * wv.y + av.z * wv.z + av.w * wv.w;
    }
    anspart[((size_t)kc * 16 + b) * HH + c * 16 + j] = acc;
}

// ---------------- K6 k_gemm: split-bf16 MFMA GEMM, W-lo via global->reg, 3 blocks/CU ----------------
// BM=128 x BN=128, BK=32, 4 waves (2x2), wave tile 64x64, 3-term split (R6 skeleton).
// LDS per buffer 24KB: AH[8][1KB] @0, AL @8K, WH @16K; double-buffered = 48KB
// -> 3 blocks/CU. W-lo fragments (wave-private, L2-resident 4MB) loaded
// global->VGPR at iter top, consumed by the LAST 16 MFMAs (issue-early/use-late
// within one iteration — no cross-barrier register rotation).
// XCD swizzle: each XCD owns an 8bm x 8bn square region.
__global__ __launch_bounds__(256, 3)
void k_gemm(const short* __restrict__ apk_hi, const short* __restrict__ apk_lo,
            const short* __restrict__ wpk_hi, const short* __restrict__ wpk_lo,
            const float* __restrict__ Cb, const float* __restrict__ ln_g,
            const float* __restrict__ w_end1, float* __restrict__ part) {
    extern __shared__ char smem[];  // 49152
    const int t = threadIdx.x;
    const int l = t & 63, w = t >> 6;
    const int wr = w >> 1, wc = w & 1;
    const int wg = blockIdx.x;
    const int xcd = wg & 7;
    const int local = wg >> 3;          // 0..63
    const int bm = xcd * 8 + (local >> 3);
    const int bn = local & 7;
    const int row0 = bm * 128;
    const int b = row0 >> 9;

    f32x4 acc[4][4];
#pragma unroll
    for (int m = 0; m < 4; ++m)
#pragma unroll
        for (int n = 0; n < 4; ++n) acc[m][n] = (f32x4){0.f, 0.f, 0.f, 0.f};

    const short8_t* WLo = (const short8_t*)wpk_lo;
    // wave's W-lo fragment (n, ks): WLo[wlb + n*2048 + ks*64]
    const size_t wlb = ((size_t)(bn * 8 + wc * 4)) * 2048 + l;

    // per-wave staging: 6 x global_load_lds (2 AH, 2 AL, 2 WH frags)
#define STAGE(buf, ks)                                                                   \
    {                                                                                    \
        const size_t abase = (size_t)(bm * 32 + (ks)) * 8 * 512;                         \
        const size_t wbase = ((size_t)(bn * 8) * 32 + (ks)) * 512;                       \
        char* lb = smem + (buf) * 24576;                                                 \
        _Pragma("unroll") for (int q = 0; q < 2; ++q) {                                  \
            const int fr = w + q * 4;                                                    \
            gld16(apk_hi + abase + fr * 512 + l * 8, lb + fr * 1024);                    \
            gld16(apk_lo + abase + fr * 512 + l * 8, lb + 8192 + fr * 1024);             \
            gld16(wpk_hi + wbase + (size_t)fr * 32 * 512 + l * 8, lb + 16384 + fr * 1024); \
        }                                                                                \
    }

    STAGE(0, 0);
    __syncthreads();

    for (int ks = 0; ks < 32; ++ks) {
        const int buf = ks & 1;
        // issue-early: this iter's W-lo fragments (global, L2-resident)
        short8_t wl[4];
#pragma unroll
        for (int n = 0; n < 4; ++n) wl[n] = WLo[wlb + (size_t)n * 2048 + ks * 64];
        if (ks < 31) STAGE(buf ^ 1, ks + 1);
        {
            const char* base_ = smem + buf * 24576;
            short8_t ah[4], al[4], wh[4];
#pragma unroll
            for (int m = 0; m < 4; ++m) {
                const int mtl = wr * 4 + m;
                ah[m] = *(const short8_t*)(base_ + (mtl << 10) + (l << 4));
                al[m] = *(const short8_t*)(base_ + 8192 + (mtl << 10) + (l << 4));
            }
#pragma unroll
            for (int n = 0; n < 4; ++n) {
                const int ntl = wc * 4 + n;
                wh[n] = *(const short8_t*)(base_ + 16384 + (ntl << 10) + (l << 4));
            }
            __builtin_amdgcn_s_setprio(1);
            // W-hi cluster first (32 MFMA) — gives wl loads ~300cy of cover
#pragma unroll
            for (int n = 0; n < 4; ++n)
#pragma unroll
                for (int m = 0; m < 4; ++m) {
                    acc[m][n] = __builtin_amdgcn_mfma_f32_16x16x32_bf16(ah[m], wh[n], acc[m][n], 0, 0, 0);
                    acc[m][n] = __builtin_amdgcn_mfma_f32_16x16x32_bf16(al[m], wh[n], acc[m][n], 0, 0, 0);
                }
            // W-lo cluster last (16 MFMA)
#pragma unroll
            for (int n = 0; n < 4; ++n)
#pragma unroll
                for (int m = 0; m < 4; ++m)
                    acc[m][n] = __builtin_amdgcn_mfma_f32_16x16x32_bf16(ah[m], wl[n], acc[m][n], 0, 0, 0);
            __builtin_amdgcn_s_setprio(0);
        }
        __syncthreads();
    }
#undef STAGE

    // ---- epilogue: per-block partial (S,Q,G) over this 128-col slice ----
    float cbv[KT][4], gwv[4];
#pragma unroll
    for (int n = 0; n < 4; ++n) {
        const int col = bn * 128 + wc * 64 + n * 16 + (l & 15);
        gwv[n] = ln_g[col] * w_end1[col];
#pragma unroll
        for (int k = 0; k < KT; ++k) cbv[k][n] = Cb[(size_t)(b * KT + k) * HH + col];
    }
    float* scr = (float*)smem;  // [wc 2][row 128][k 5][3] = 15360 B

    for (int k = 0; k < KT; ++k) {
        float S[4][4], Q[4][4], G[4][4];
#pragma unroll
        for (int m = 0; m < 4; ++m)
#pragma unroll
            for (int r = 0; r < 4; ++r) { S[m][r] = 0.f; Q[m][r] = 0.f; G[m][r] = 0.f; }
#pragma unroll
        for (int n = 0; n < 4; ++n) {
            const float cb = cbv[k][n];
            const float gwn = gwv[n];
#pragma unroll
            for (int m = 0; m < 4; ++m)
#pragma unroll
                for (int r = 0; r < 4; ++r) {
                    float v = tanh_fast(acc[m][n][r] + cb);
                    S[m][r] += v;
                    Q[m][r] += v * v;
                    G[m][r] += v * gwn;
                }
        }
        for (int msk = 1; msk < 16; msk <<= 1) {
#pragma unroll
            for (int m = 0; m < 4; ++m)
#pragma unroll
                for (int r = 0; r < 4; ++r) {
                    S[m][r] += __shfl_xor(S[m][r], msk);
                    Q[m][r] += __shfl_xor(Q[m][r], msk);
                    G[m][r] += __shfl_xor(G[m][r], msk);
                }
        }
        if ((l & 15) == 0) {
            const int gg = l >> 4;
#pragma unroll
            for (int m = 0; m < 4; ++m)
#pragma unroll
                for (int r = 0; r < 4; ++r) {
                    const int row = wr * 64 + m * 16 + gg * 4 + r;
                    float* sp_ = scr + ((wc * 128 + row) * KT + k) * 3;
                    sp_[0] = S[m][r];
                    sp_[1] = Q[m][r];
                    sp_[2] = G[m][r];
                }
        }
    }
    __syncthreads();

#pragma unroll
    for (int i = 0; i < 3; ++i) {
        const int idx = i * 256 + t;  // 640 = 128 rows * 5 k
        if (idx < 128 * KT) {
            const int row = idx / KT, k = idx % KT;
            const float* a_ = scr + ((0 * 128 + row) * KT + k) * 3;
            const float* b_ = scr + ((1 * 128 + row) * KT + k) * 3;
            float4 o;
            o.x = a_[0] + b_[0];
            o.y = a_[1] + b_[1];
            o.z = a_[2] + b_[2];
            o.w = 0.f;
            *(float4*)(part + (((size_t)bn * (BB * SS) + row0 + row) * KT + k) * 4) = o;
        }
    }
}

// ---------------- K7 final: epi2+softmax_end fused (80) | ansred (16) ----------------
__global__ void k_final(const float* __restrict__ part, const float* __restrict__ p_mask,
                        const float* __restrict__ scal, const float* __restrict__ b_end1,
                        const float* __restrict__ anspart, const float* __restrict__ b_ans0,
                        const float* __restrict__ w_ans1, float* __restrict__ out) {
    const int bid = blockIdx.x;
    const int t = threadIdx.x;
    __shared__ float rscr[4];

    if (bid < 80) {
        // ---- epi2 (compute masked end logits for this (b,k)) + softmax + top-5 ----
        const int b = bid / KT, k = bid % KT;
        const float GW1 = scal[0], BW1 = scal[1], be1 = b_end1[0];
        float x01[2];
#pragma unroll
        for (int h = 0; h < 2; ++h) {
            const int s = h * 256 + t;
            const int row = b * SS + s;
            float S = 0.f, Q = 0.f, G = 0.f;
#pragma unroll
            for (int bn = 0; bn < 8; ++bn) {
                float4 v = *(const float4*)(part + (((size_t)bn * (BB * SS) + row) * KT + k) * 4);
                S += v.x;
                Q += v.y;
                G += v.z;
            }
            const float mu = S * (1.f / HH);
            const float var = Q * (1.f / HH) - mu * mu;
            const float rs = rsqrtf(var + 1e-12f);
            const float logit = rs * (G - mu * GW1) + BW1 + be1;
            const float pm = p_mask[row];
            x01[h] = logit * (1.f - pm) - NEGV * pm;
        }
        softmax_topk_vals<false>(x01[0], x01[1], nullptr,
                                 out + 160 + b * 25 + k * KT, out + 560 + b * 25 + k * KT, nullptr);
    } else {
        // ---- ansred: cls_logits ----
        const int b = bid - 80;
        float dsum = 0.f;
#pragma unroll
        for (int q = 0; q < 4; ++q) {
            const int h = q * 256 + t;
            float s = b_ans0[h];
#pragma unroll
            for (int kc = 0; kc < 16; ++kc) s += anspart[((size_t)kc * 16 + b) * HH + h];
            dsum += tanhf(s) * w_ans1[h];
        }
        dsum = wave_sum(dsum);
        if ((t & 63) == 0) rscr[t >> 6] = dsum;
        __syncthreads();
        if (t == 0) out[960 + b] = rscr[0] + rscr[1] + rscr[2] + rscr[3];
    }
}

// ---------------- launch ----------------
extern "C" void kernel_launch(void* const* d_in, const int* in_sizes, int n_in,
                              void* d_out, int out_size, void* d_ws, size_t ws_size,
                              hipStream_t stream) {
    const float* seq     = (const float*)d_in[0];
    const float* p_mask  = (const float*)d_in[1];
    const float* w_start = (const float*)d_in[2];
    const float* b_start = (const float*)d_in[3];
    const float* w_end0  = (const float*)d_in[4];
    const float* b_end0  = (const float*)d_in[5];
    const float* ln_g    = (const float*)d_in[6];
    const float* ln_b    = (const float*)d_in[7];
    const float* w_end1  = (const float*)d_in[8];
    const float* b_end1  = (const float*)d_in[9];
    const float* w_ans0  = (const float*)d_in[10];
    const float* b_ans0  = (const float*)d_in[11];
    const float* w_ans1  = (const float*)d_in[12];
    float* out = (float*)d_out;

    float* sm      = (float*)d_ws;                  // 8192
    float* sp      = sm + BB * SS;                  // 8192
    float* partial = sp + BB * SS;                  // 524288
    float* feat    = partial + BB * 32 * HH;        // 32768
    float* Cb      = feat + BB * 2048;              // 81920
    float* Cpart   = Cb + 80 * HH;                  // 655360
    float* anspart = Cpart + 8 * 80 * HH;           // 262144
    float* scal    = anspart + 16 * BB * HH;        // 16
    int*   idx     = (int*)(scal + 16);             // 80
    float* part    = (float*)(((uintptr_t)(idx + 80) + 255) & ~(uintptr_t)255);  // 1310720 floats
    short* wpk_hi  = (short*)(part + 8 * BB * SS * KT * 4);
    short* wpk_lo  = wpk_hi + (1 << 20);            // 1M bf16 each
    short* apk_hi  = wpk_lo + (1 << 20);            // 8M bf16 each
    short* apk_lo  = apk_hi + (1 << 23);

    hipLaunchKernelGGL(k_mega, dim3(6657), dim3(256), 0, stream,
                       seq, w_end0, p_mask, w_start, b_start, ln_g, ln_b, w_end1,
                       wpk_hi, wpk_lo, apk_hi, apk_lo, sm, scal);
    hipLaunchKernelGGL(k_softmax_start, dim3(BB), dim3(256), 0, stream, sm, sp, out, idx);
    hipLaunchKernelGGL(k_mid, dim3(1024), dim3(256), 0, stream,
                       seq, idx, w_end0, Cpart, sp, partial);
    hipLaunchKernelGGL(k_red, dim3(96), dim3(256), 0, stream,
                       Cpart, b_end0, Cb, seq, partial, feat);
    hipLaunchKernelGGL(k_ans, dim3(1024), dim3(256), 0, stream, feat, w_ans0, anspart);
    hipLaunchKernelGGL(k_gemm, dim3(512), dim3(256), 49152, stream,
                       apk_hi, apk_lo, wpk_hi, wpk_lo, Cb, ln_g, w_end1, part);
    hipLaunchKernelGGL(k_final, dim3(96), dim3(256), 0, stream,
                       part, p_mask, scal, b_end1, anspart, b_ans0, w_ans1, out);
}

// Round 14
// 123.862 us; speedup vs baseline: 1.2071x; 1.0571x over previous
//
#include <hip/hip_runtime.h>
#include <math.h>

#define BB 16
#define SS 512
#define HH 1024
#define KT 5
#define NEGV 1e30f

typedef __attribute__((ext_vector_type(8))) short short8_t;
typedef __attribute__((ext_vector_type(4))) float f32x4;

// ---------------- helpers ----------------
__device__ __forceinline__ float wave_sum(float v) {
    for (int off = 32; off; off >>= 1) v += __shfl_down(v, off);
    return v;
}

__device__ __forceinline__ unsigned short bf16rn(float x) {
    unsigned u = __float_as_uint(x);
    return (unsigned short)((u + 0x7fffu + ((u >> 16) & 1u)) >> 16);
}

__device__ __forceinline__ void split2(float x, unsigned short& h, unsigned short& l) {
    h = bf16rn(x);
    float hf = __uint_as_float(((unsigned)h) << 16);
    l = bf16rn(x - hf);
}

__device__ __forceinline__ float tanh_fast(float x) {
    float e = __expf(2.0f * x);
    return 1.0f - 2.0f * __builtin_amdgcn_rcpf(e + 1.0f);
}

// async global->LDS, 16B per lane; lds dst must be wave-uniform base
__device__ __forceinline__ void gld16(const void* g, char* l) {
    __builtin_amdgcn_global_load_lds((const __attribute__((address_space(1))) void*)g,
                                     (__attribute__((address_space(3))) void*)l, 16, 0, 0);
}

// ---------------- softmax + top-5 over 512 values held as (x0,x1) per thread ----------------
template <bool WRITE_P>
__device__ void softmax_topk_vals(float x0, float x1, float* __restrict__ p_out,
                                  float* __restrict__ val_out, float* __restrict__ idxf_out,
                                  int* __restrict__ idxi_out) {
    const int t = threadIdx.x;
    __shared__ float scr[4];
    __shared__ float sv[4];
    __shared__ int si[4];
    __shared__ int wi_s;

    float m = fmaxf(x0, x1);
    for (int off = 32; off; off >>= 1) m = fmaxf(m, __shfl_down(m, off));
    if ((t & 63) == 0) scr[t >> 6] = m;
    __syncthreads();
    m = fmaxf(fmaxf(scr[0], scr[1]), fmaxf(scr[2], scr[3]));
    __syncthreads();

    float e0 = expf(x0 - m), e1 = expf(x1 - m);
    float ssum = wave_sum(e0 + e1);
    if ((t & 63) == 0) scr[t >> 6] = ssum;
    __syncthreads();
    ssum = scr[0] + scr[1] + scr[2] + scr[3];
    __syncthreads();

    if (WRITE_P) {
        p_out[t] = e0 / ssum;
        p_out[t + 256] = e1 / ssum;
    }
    const float lse = m + logf(ssum);

    float v0 = x0, v1 = x1;
    for (int k = 0; k < KT; ++k) {
        float bv;
        int bi;
        if (v0 >= v1) { bv = v0; bi = t; } else { bv = v1; bi = t + 256; }
        for (int off = 32; off; off >>= 1) {
            float ov = __shfl_down(bv, off);
            int oi = __shfl_down(bi, off);
            if (ov > bv || (ov == bv && oi < bi)) { bv = ov; bi = oi; }
        }
        if ((t & 63) == 0) { sv[t >> 6] = bv; si[t >> 6] = bi; }
        __syncthreads();
        if (t == 0) {
            float fv = sv[0];
            int fi = si[0];
            for (int w = 1; w < 4; ++w)
                if (sv[w] > fv || (sv[w] == fv && si[w] < fi)) { fv = sv[w]; fi = si[w]; }
            wi_s = fi;
            val_out[k] = fv - lse;
            idxf_out[k] = (float)fi;
            if (idxi_out) idxi_out[k] = fi;
        }
        __syncthreads();
        const int wi = wi_s;
        if (wi == t) v0 = -INFINITY;
        else if (wi == t + 256) v1 = -INFINITY;
        __syncthreads();
    }
}

// ---------------- K1 mega_prep: seqpk | prep | start_logits | scal ----------------
// grid = 4096 (seqpk) + 512 (prep) + 2048 (start_logits) + 1 (scal) = 6657
__global__ void k_mega(const float* __restrict__ seq, const float* __restrict__ w_end0,
                       const float* __restrict__ pm, const float* __restrict__ w_start,
                       const float* __restrict__ b_start, const float* __restrict__ ln_g,
                       const float* __restrict__ ln_b, const float* __restrict__ w_end1,
                       short* __restrict__ wpk_hi, short* __restrict__ wpk_lo,
                       short* __restrict__ apk_hi, short* __restrict__ apk_lo,
                       float* __restrict__ sm, float* __restrict__ scal) {
    const int bid = blockIdx.x;
    const int t = threadIdx.x;
    __shared__ float scr8[8];

    if (bid < 4096) {
        // ---- seqpk: pack seq into MFMA A-frag order (bf16 hi/lo) ----
        // Apk layout: [bm(64)][ks(32)][mtl(8)][lane(64)][8] bf16
        const size_t g = (size_t)bid * 256 + t;
        const int l = g & 63;
        const int mtl = (g >> 6) & 7;
        const int ks = (g >> 9) & 31;
        const int bm = g >> 14;
        const int row = bm * 128 + mtl * 16 + (l & 15);
        const int k0 = ks * 32 + (l >> 4) * 8;
        const float4 v0 = *(const float4*)(seq + (size_t)row * HH + k0);
        const float4 v1 = *(const float4*)(seq + (size_t)row * HH + k0 + 4);
        float xs[8] = {v0.x, v0.y, v0.z, v0.w, v1.x, v1.y, v1.z, v1.w};
        unsigned short h[8], lo[8];
#pragma unroll
        for (int j = 0; j < 8; ++j) split2(xs[j], h[j], lo[j]);
        short8_t hv, lv;
#pragma unroll
        for (int j = 0; j < 8; ++j) { hv[j] = (short)h[j]; lv[j] = (short)lo[j]; }
        *(short8_t*)(apk_hi + g * 8) = hv;
        *(short8_t*)(apk_lo + g * 8) = lv;
    } else if (bid < 4608) {
        // ---- prep: pack W0a into MFMA B-frag order (bf16 hi/lo) ----
        const int bid2 = bid - 4096;
        const int nt = bid2 & 63;
        const int yy = bid2 >> 6;
        const int n_idx = t & 15;
        const int g = (t >> 4) & 3;
        const int kq = t >> 6;
        const int kblk = yy * 4 + kq;
        const int k0 = kblk * 32 + g * 8;
        unsigned short hs[8], ls[8];
#pragma unroll
        for (int j = 0; j < 8; ++j) {
            float v = w_end0[(size_t)(k0 + j) * HH + nt * 16 + n_idx];
            split2(v, hs[j], ls[j]);
        }
        const size_t fi = (((size_t)nt * 32 + kblk) * 64 + (g * 16 + n_idx)) * 8;
        short8_t hv, lv;
#pragma unroll
        for (int j = 0; j < 8; ++j) { hv[j] = (short)hs[j]; lv[j] = (short)ls[j]; }
        *(short8_t*)(wpk_hi + fi) = hv;
        *(short8_t*)(wpk_lo + fi) = lv;
    } else if (bid < 6656) {
        // ---- start_logits: wave per row ----
        const int l = t & 63;
        const int row = (bid - 4608) * 4 + (t >> 6);
        const float4* rp = (const float4*)(seq + (size_t)row * HH);
        const float4* wp = (const float4*)w_start;
        float d = 0.f;
#pragma unroll
        for (int q = 0; q < 4; ++q) {
            float4 a = rp[q * 64 + l];
            float4 w = wp[q * 64 + l];
            d += a.x * w.x + a.y * w.y + a.z * w.z + a.w * w.w;
        }
        d = wave_sum(d);
        if (l == 0) {
            float m = pm[row];
            sm[row] = (d + b_start[0]) * (1.f - m) - NEGV * m;
        }
    } else {
        // ---- scal: GW1 = sum g*w1, BW1 = sum b*w1 ----
        float4 g = ((const float4*)ln_g)[t];
        float4 w = ((const float4*)w_end1)[t];
        float4 b = ((const float4*)ln_b)[t];
        float gw = g.x * w.x + g.y * w.y + g.z * w.z + g.w * w.w;
        float bw = b.x * w.x + b.y * w.y + b.z * w.z + b.w * w.w;
        gw = wave_sum(gw);
        bw = wave_sum(bw);
        if ((t & 63) == 0) { scr8[t >> 6] = gw; scr8[4 + (t >> 6)] = bw; }
        __syncthreads();
        if (t == 0) {
            scal[0] = scr8[0] + scr8[1] + scr8[2] + scr8[3];
            scal[1] = scr8[4] + scr8[5] + scr8[6] + scr8[7];
        }
    }
}

// ---------------- K2: softmax_start (start top-5 + probs) ----------------
__global__ void k_softmax_start(const float* __restrict__ sm, float* __restrict__ sp,
                                float* __restrict__ dout, int* __restrict__ idx) {
    const int b = blockIdx.x;
    const int t = threadIdx.x;
    const float* x = sm + (size_t)b * SS;
    softmax_topk_vals<true>(x[t], x[t + 256], sp + (size_t)b * SS,
                            dout + b * KT, dout + 80 + b * KT, idx + b * KT);
}

// ---------------- K3 mid: cfeat (512 blocks) | sf_partial (512 blocks) ----------------
__global__ void k_mid(const float* __restrict__ seq, const int* __restrict__ idx,
                      const float* __restrict__ w_end0, float* __restrict__ Cpart,
                      const float* __restrict__ sp, float* __restrict__ partial) {
    __shared__ float shA[80 * 132];
    __shared__ float shW[16 * 132];
    __shared__ int growL[80];
    const int bid = blockIdx.x;
    const int t = threadIdx.x;

    if (bid < 512) {
        // ---- cfeat: Cb partials, K-split ----
        const int c = bid & 63;
        const int kc = bid >> 6;
        if (t < 80) growL[t] = (t / KT) * SS + idx[t];
        __syncthreads();
        for (int i = 0; i < 40; ++i) {
            const int e = i * 256 + t;
            const int r = e >> 7, d = e & 127;
            shA[r * 132 + d] = seq[(size_t)growL[r] * HH + kc * 128 + d];
        }
#pragma unroll
        for (int p = 0; p < 8; ++p) {
            const int e = p * 256 + t;
            const int d = e >> 4, j = e & 15;
            shW[j * 132 + d] = w_end0[(size_t)(HH + kc * 128 + d) * HH + c * 16 + j];
        }
        __syncthreads();
        const int j = t & 15, rg = t >> 4;
        const float4* A4 = (const float4*)shA;
        const float4* W4 = (const float4*)shW;
        float acc[5] = {0.f, 0.f, 0.f, 0.f, 0.f};
        for (int d4 = 0; d4 < 32; ++d4) {
            float4 wv = W4[j * 33 + d4];
#pragma unroll
            for (int i = 0; i < 5; ++i) {
                float4 av = A4[(rg + 16 * i) * 33 + d4];
                acc[i] += av.x * wv.x + av.y * wv.y + av.z * wv.z + av.w * wv.w;
            }
        }
#pragma unroll
        for (int i = 0; i < 5; ++i)
            Cpart[((size_t)kc * 80 + rg + 16 * i) * HH + c * 16 + j] = acc[i];
    } else {
        // ---- sf_partial: start_feature partial sums (16-row chunks) ----
        const int bid2 = bid - 512;
        const int chunk = bid2 & 31;
        const int b = bid2 >> 5;
        if (t < 16) shA[t] = sp[b * SS + chunk * 16 + t];
        __syncthreads();
        float4 acc = make_float4(0.f, 0.f, 0.f, 0.f);
        const float4* base = (const float4*)(seq + ((size_t)b * SS + chunk * 16) * HH);
        for (int s = 0; s < 16; ++s) {
            float4 v = base[(size_t)s * 256 + t];
            float ps = shA[s];
            acc.x = fmaf(ps, v.x, acc.x);
            acc.y = fmaf(ps, v.y, acc.y);
            acc.z = fmaf(ps, v.z, acc.z);
            acc.w = fmaf(ps, v.w, acc.w);
        }
        ((float4*)partial)[(size_t)(b * 32 + chunk) * 256 + t] = acc;
    }
}

// ---------------- K4 red: cbred (80) | featsum (16) ----------------
__global__ void k_red(const float* __restrict__ Cpart, const float* __restrict__ b_end0,
                      float* __restrict__ Cb, const float* __restrict__ seq,
                      const float* __restrict__ partial, float* __restrict__ feat) {
    const int bid = blockIdx.x;
    const int t = threadIdx.x;
    if (bid < 80) {
        const int bk = bid;
#pragma unroll
        for (int q = 0; q < 4; ++q) {
            const int h = q * 256 + t;
            float s = b_end0[h];
#pragma unroll
            for (int kc = 0; kc < 8; ++kc) s += Cpart[((size_t)kc * 80 + bk) * HH + h];
            Cb[(size_t)bk * HH + h] = s;
        }
    } else {
        const int b = bid - 80;
        for (int q = 0; q < 4; ++q) {
            const int h = q * 256 + t;
            float s = 0.f;
            for (int c = 0; c < 32; ++c) s += partial[(size_t)(b * 32 + c) * HH + h];
            feat[(size_t)b * 2048 + h] = s;
            feat[(size_t)b * 2048 + HH + h] = seq[(size_t)b * SS * HH + h];
        }
    }
}

// ---------------- K5 k_gemm_ans: [bid<512] 2D-tiled split-bf16 MFMA GEMM (R6/R9 proven)
//                   | [bid>=512] ans-head GEMM partials (1024 blocks) ----------------
__global__ __launch_bounds__(256, 2)
void k_gemm_ans(const short* __restrict__ apk_hi, const short* __restrict__ apk_lo,
                const short* __restrict__ wpk_hi, const short* __restrict__ wpk_lo,
                const float* __restrict__ Cb, const float* __restrict__ ln_g,
                const float* __restrict__ w_end1, float* __restrict__ part,
                const float* __restrict__ feat, const float* __restrict__ w_ans0,
                float* __restrict__ anspart) {
    extern __shared__ char smem[];  // 65536
    const int t = threadIdx.x;

    if (blockIdx.x >= 512) {
        // ================= ans branch =================
        const int bid2 = blockIdx.x - 512;
        const int c = bid2 & 63;
        const int kc = bid2 >> 6;
        float* A = (float*)smem;             // 16*132
        float* W = A + 16 * 132;             // 16*132
#pragma unroll
        for (int i = 0; i < 8; ++i) {
            const int e = i * 256 + t;
            const int b = e >> 7, d = e & 127;
            A[b * 132 + d] = feat[(size_t)b * 2048 + kc * 128 + d];
        }
#pragma unroll
        for (int p = 0; p < 8; ++p) {
            const int e = p * 256 + t;
            const int d = e >> 4, j = e & 15;
            W[j * 132 + d] = w_ans0[(size_t)(kc * 128 + d) * HH + c * 16 + j];
        }
        __syncthreads();
        const int j = t & 15, b = t >> 4;
        const float4* A4 = (const float4*)A;
        const float4* W4 = (const float4*)W;
        float acc = 0.f;
        for (int d4 = 0; d4 < 32; ++d4) {
            float4 wv = W4[j * 33 + d4];
            float4 av = A4[b * 33 + d4];
            acc += av.x * wv.x + av.y * wv.y + av.z * wv.z + av.w * wv.w;
        }
        anspart[((size_t)kc * 16 + b) * HH + c * 16 + j] = acc;
        return;
    }

    // ================= gemm branch (R6/R9 proven verbatim) =================
    const int l = t & 63, w = t >> 6;
    const int wr = w >> 1, wc = w & 1;
    const int wg = blockIdx.x;
    const int xcd = wg & 7;
    const int local = wg >> 3;          // 0..63
    const int bm = xcd * 8 + (local >> 3);
    const int bn = local & 7;
    const int row0 = bm * 128;
    const int b = row0 >> 9;

    f32x4 acc[4][4];
#pragma unroll
    for (int m = 0; m < 4; ++m)
#pragma unroll
        for (int n = 0; n < 4; ++n) acc[m][n] = (f32x4){0.f, 0.f, 0.f, 0.f};

#define STAGE(buf, ks)                                                                   \
    {                                                                                    \
        const size_t abase = (size_t)(bm * 32 + (ks)) * 8 * 512;                         \
        const size_t wbase = ((size_t)(bn * 8) * 32 + (ks)) * 512;                       \
        char* lb = smem + (buf) * 32768;                                                 \
        _Pragma("unroll") for (int q = 0; q < 2; ++q) {                                  \
            const int fr = w + q * 4;                                                    \
            gld16(apk_hi + abase + fr * 512 + l * 8, lb + fr * 1024);                    \
            gld16(apk_lo + abase + fr * 512 + l * 8, lb + 8192 + fr * 1024);             \
            gld16(wpk_hi + wbase + (size_t)fr * 32 * 512 + l * 8, lb + 16384 + fr * 1024); \
            gld16(wpk_lo + wbase + (size_t)fr * 32 * 512 + l * 8, lb + 24576 + fr * 1024); \
        }                                                                                \
    }

    STAGE(0, 0);
    __syncthreads();

    for (int ks = 0; ks < 32; ++ks) {
        const int buf = ks & 1;
        if (ks < 31) STAGE(buf ^ 1, ks + 1);
        {
            const char* base_ = smem + buf * 32768;
            short8_t ah[4], al[4], wh[4], wl[4];
#pragma unroll
            for (int m = 0; m < 4; ++m) {
                const int mtl = wr * 4 + m;
                ah[m] = *(const short8_t*)(base_ + (mtl << 10) + (l << 4));
                al[m] = *(const short8_t*)(base_ + 8192 + (mtl << 10) + (l << 4));
            }
#pragma unroll
            for (int n = 0; n < 4; ++n) {
                const int ntl = wc * 4 + n;
                wh[n] = *(const short8_t*)(base_ + 16384 + (ntl << 10) + (l << 4));
                wl[n] = *(const short8_t*)(base_ + 24576 + (ntl << 10) + (l << 4));
            }
#pragma unroll
            for (int n = 0; n < 4; ++n)
#pragma unroll
                for (int m = 0; m < 4; ++m) {
                    acc[m][n] = __builtin_amdgcn_mfma_f32_16x16x32_bf16(ah[m], wh[n], acc[m][n], 0, 0, 0);
                    acc[m][n] = __builtin_amdgcn_mfma_f32_16x16x32_bf16(al[m], wh[n], acc[m][n], 0, 0, 0);
                    acc[m][n] = __builtin_amdgcn_mfma_f32_16x16x32_bf16(ah[m], wl[n], acc[m][n], 0, 0, 0);
                }
        }
        __syncthreads();
    }
#undef STAGE

    // ---- epilogue: per-block partial (S,Q,G) over this 128-col slice ----
    float cbv[KT][4], gwv[4];
#pragma unroll
    for (int n = 0; n < 4; ++n) {
        const int col = bn * 128 + wc * 64 + n * 16 + (l & 15);
        gwv[n] = ln_g[col] * w_end1[col];
#pragma unroll
        for (int k = 0; k < KT; ++k) cbv[k][n] = Cb[(size_t)(b * KT + k) * HH + col];
    }
    float* scr = (float*)smem;  // [wc 2][row 128][k 5][3]

    for (int k = 0; k < KT; ++k) {
        float S[4][4], Q[4][4], G[4][4];
#pragma unroll
        for (int m = 0; m < 4; ++m)
#pragma unroll
            for (int r = 0; r < 4; ++r) { S[m][r] = 0.f; Q[m][r] = 0.f; G[m][r] = 0.f; }
#pragma unroll
        for (int n = 0; n < 4; ++n) {
            const float cb = cbv[k][n];
            const float gwn = gwv[n];
#pragma unroll
            for (int m = 0; m < 4; ++m)
#pragma unroll
                for (int r = 0; r < 4; ++r) {
                    float v = tanh_fast(acc[m][n][r] + cb);
                    S[m][r] += v;
                    Q[m][r] += v * v;
                    G[m][r] += v * gwn;
                }
        }
        for (int msk = 1; msk < 16; msk <<= 1) {
#pragma unroll
            for (int m = 0; m < 4; ++m)
#pragma unroll
                for (int r = 0; r < 4; ++r) {
                    S[m][r] += __shfl_xor(S[m][r], msk);
                    Q[m][r] += __shfl_xor(Q[m][r], msk);
                    G[m][r] += __shfl_xor(G[m][r], msk);
                }
        }
        if ((l & 15) == 0) {
            const int gg = l >> 4;
#pragma unroll
            for (int m = 0; m < 4; ++m)
#pragma unroll
                for (int r = 0; r < 4; ++r) {
                    const int row = wr * 64 + m * 16 + gg * 4 + r;
                    float* sp_ = scr + ((wc * 128 + row) * KT + k) * 3;
                    sp_[0] = S[m][r];
                    sp_[1] = Q[m][r];
                    sp_[2] = G[m][r];
                }
        }
    }
    __syncthreads();

#pragma unroll
    for (int i = 0; i < 3; ++i) {
        const int idx = i * 256 + t;  // 640 = 128 rows * 5 k
        if (idx < 128 * KT) {
            const int row = idx / KT, k = idx % KT;
            const float* a_ = scr + ((0 * 128 + row) * KT + k) * 3;
            const float* b_ = scr + ((1 * 128 + row) * KT + k) * 3;
            float4 o;
            o.x = a_[0] + b_[0];
            o.y = a_[1] + b_[1];
            o.z = a_[2] + b_[2];
            o.w = 0.f;
            *(float4*)(part + (((size_t)bn * (BB * SS) + row0 + row) * KT + k) * 4) = o;
        }
    }
}

// ---------------- K7 final: epi2+softmax_end fused (80) | ansred (16) ----------------
__global__ void k_final(const float* __restrict__ part, const float* __restrict__ p_mask,
                        const float* __restrict__ scal, const float* __restrict__ b_end1,
                        const float* __restrict__ anspart, const float* __restrict__ b_ans0,
                        const float* __restrict__ w_ans1, float* __restrict__ out) {
    const int bid = blockIdx.x;
    const int t = threadIdx.x;
    __shared__ float rscr[4];

    if (bid < 80) {
        // ---- epi2 (compute masked end logits for this (b,k)) + softmax + top-5 ----
        const int b = bid / KT, k = bid % KT;
        const float GW1 = scal[0], BW1 = scal[1], be1 = b_end1[0];
        float x01[2];
#pragma unroll
        for (int h = 0; h < 2; ++h) {
            const int s = h * 256 + t;
            const int row = b * SS + s;
            float S = 0.f, Q = 0.f, G = 0.f;
#pragma unroll
            for (int bn = 0; bn < 8; ++bn) {
                float4 v = *(const float4*)(part + (((size_t)bn * (BB * SS) + row) * KT + k) * 4);
                S += v.x;
                Q += v.y;
                G += v.z;
            }
            const float mu = S * (1.f / HH);
            const float var = Q * (1.f / HH) - mu * mu;
            const float rs = rsqrtf(var + 1e-12f);
            const float logit = rs * (G - mu * GW1) + BW1 + be1;
            const float pm = p_mask[row];
            x01[h] = logit * (1.f - pm) - NEGV * pm;
        }
        softmax_topk_vals<false>(x01[0], x01[1], nullptr,
                                 out + 160 + b * 25 + k * KT, out + 560 + b * 25 + k * KT, nullptr);
    } else {
        // ---- ansred: cls_logits ----
        const int b = bid - 80;
        float dsum = 0.f;
#pragma unroll
        for (int q = 0; q < 4; ++q) {
            const int h = q * 256 + t;
            float s = b_ans0[h];
#pragma unroll
            for (int kc = 0; kc < 16; ++kc) s += anspart[((size_t)kc * 16 + b) * HH + h];
            dsum += tanhf(s) * w_ans1[h];
        }
        dsum = wave_sum(dsum);
        if ((t & 63) == 0) rscr[t >> 6] = dsum;
        __syncthreads();
        if (t == 0) out[960 + b] = rscr[0] + rscr[1] + rscr[2] + rscr[3];
    }
}

// ---------------- launch ----------------
extern "C" void kernel_launch(void* const* d_in, const int* in_sizes, int n_in,
                              void* d_out, int out_size, void* d_ws, size_t ws_size,
                              hipStream_t stream) {
    const float* seq     = (const float*)d_in[0];
    const float* p_mask  = (const float*)d_in[1];
    const float* w_start = (const float*)d_in[2];
    const float* b_start = (const float*)d_in[3];
    const float* w_end0  = (const float*)d_in[4];
    const float* b_end0  = (const float*)d_in[5];
    const float* ln_g    = (const float*)d_in[6];
    const float* ln_b    = (const float*)d_in[7];
    const float* w_end1  = (const float*)d_in[8];
    const float* b_end1  = (const float*)d_in[9];
    const float* w_ans0  = (const float*)d_in[10];
    const float* b_ans0  = (const float*)d_in[11];
    const float* w_ans1  = (const float*)d_in[12];
    float* out = (float*)d_out;

    float* sm      = (float*)d_ws;                  // 8192
    float* sp      = sm + BB * SS;                  // 8192
    float* partial = sp + BB * SS;                  // 524288
    float* feat    = partial + BB * 32 * HH;        // 32768
    float* Cb      = feat + BB * 2048;              // 81920
    float* Cpart   = Cb + 80 * HH;                  // 655360
    float* anspart = Cpart + 8 * 80 * HH;           // 262144
    float* scal    = anspart + 16 * BB * HH;        // 16
    int*   idx     = (int*)(scal + 16);             // 80
    float* part    = (float*)(((uintptr_t)(idx + 80) + 255) & ~(uintptr_t)255);  // 1310720 floats
    short* wpk_hi  = (short*)(part + 8 * BB * SS * KT * 4);
    short* wpk_lo  = wpk_hi + (1 << 20);            // 1M bf16 each
    short* apk_hi  = wpk_lo + (1 << 20);            // 8M bf16 each
    short* apk_lo  = apk_hi + (1 << 23);

    hipLaunchKernelGGL(k_mega, dim3(6657), dim3(256), 0, stream,
                       seq, w_end0, p_mask, w_start, b_start, ln_g, ln_b, w_end1,
                       wpk_hi, wpk_lo, apk_hi, apk_lo, sm, scal);
    hipLaunchKernelGGL(k_softmax_start, dim3(BB), dim3(256), 0, stream, sm, sp, out, idx);
    hipLaunchKernelGGL(k_mid, dim3(1024), dim3(256), 0, stream,
                       seq, idx, w_end0, Cpart, sp, partial);
    hipLaunchKernelGGL(k_red, dim3(96), dim3(256), 0, stream,
                       Cpart, b_end0, Cb, seq, partial, feat);
    hipLaunchKernelGGL(k_gemm_ans, dim3(512 + 1024), dim3(256), 65536, stream,
                       apk_hi, apk_lo, wpk_hi, wpk_lo, Cb, ln_g, w_end1, part,
                       feat, w_ans0, anspart);
    hipLaunchKernelGGL(k_final, dim3(96), dim3(256), 0, stream,
                       part, p_mask, scal, b_end1, anspart, b_ans0, w_ans1, out);
}